// Round 9
// baseline (956.929 us; speedup 1.0000x reference)
//
#include <hip/hip_runtime.h>
#include <hip/hip_bf16.h>
#include <cstddef>
#include <cstdint>

// ---------- types ----------
typedef __bf16 bf16;
typedef bf16 bf16x8 __attribute__((ext_vector_type(8)));
typedef float f32x4 __attribute__((ext_vector_type(4)));

#define DEV static __device__ __forceinline__

DEV f32x4 mfma_bf16(bf16x8 a, bf16x8 b, f32x4 c) {
  return __builtin_amdgcn_mfma_f32_16x16x32_bf16(a, b, c, 0, 0, 0);
}
DEV f32x4 mfma_fp8(long a, long b, f32x4 c) {
  return __builtin_amdgcn_mfma_f32_16x16x32_fp8_fp8(a, b, c, 0, 0, 0);
}

DEV float sigmoid_f(float x) { return 1.0f / (1.0f + __expf(-x)); }
DEV float tanh_f(float x) {
  float ax = fabsf(x);
  float e = __expf(-2.0f * ax);
  float t = 1.0f - 2.0f * e / (1.0f + e);
  return copysignf(t, x);
}
DEV unsigned char fp8_of(float x) {
  return (unsigned char)(__builtin_amdgcn_cvt_pk_fp8_f32(x, x, 0, false) & 0xFF);
}

// ---------- problem constants: T=32,N=64,C=64,L=64,H=256,NA=16,NL=128 ----------
static constexpr int H_ = 256;

// ---------- canonical bf16 weight region: element offsets ----------
static constexpr int o_embed = 0;
static constexpr int o_aemb = 32768;
static constexpr int o_wi_f = 36864;
static constexpr int o_wh_f = 233472;
static constexpr int o_bi_f = 430080;
static constexpr int o_bh_f = 430848;
static constexpr int o_wi_b = 431616;
static constexpr int o_wh_b = 628224;
static constexpr int o_bi_b = 824832;
static constexpr int o_bh_b = 825600;
static constexpr int o_f_w1 = 826368;
static constexpr int o_f_b1 = 908288;
static constexpr int o_f_w2 = 908544;
static constexpr int o_f_b2 = 974080;
static constexpr int o_cell_wi = 974336;
static constexpr int o_cell_wh = 1170944;
static constexpr int o_cell_bi = 1367552;
static constexpr int o_cell_bh = 1368320;
static constexpr int o_critic_w = 1369088;
static constexpr int o_critic_b = 1369344;
static constexpr int o_pointer_w = 1369360;
static constexpr int o_pointer_b = 1385744;
static constexpr int o_actor_w = 1385808;
static constexpr int o_actor_b = 1389904;
static constexpr int o_query_w = 1389920;
static constexpr int o_query_b = 1455456;
static constexpr int CW_TOTAL = 1455712;
static constexpr int WH8_TOTAL = 393216;  // fp8 [2][768][256]
static constexpr int PREP_TOTAL = CW_TOTAL + WH8_TOTAL;
static constexpr int PREP_WGS = (PREP_TOTAL + 2047) / 2048;  // 903

// ---------- workspace layout (bytes) ----------
static constexpr size_t XI_OFF = 0;                               // bf16 [2][4096 grow][768]
static constexpr size_t XI_BYTES = 2ull * 4096 * 768 * 2;         // 12.58 MB
static constexpr size_t K1_OFF = XI_OFF + XI_BYTES;
static constexpr size_t K1_BYTES = 64ull * 32 * 128 * 256;        // 67.1 MB
static constexpr size_t GI_OFF = K1_OFF + K1_BYTES;
static constexpr size_t GI_BYTES = 32ull * 64 * 768 * 4;
static constexpr size_t HD_OFF = GI_OFF + GI_BYTES;
static constexpr size_t HD_BYTES = 32ull * 64 * 256 * 4;
static constexpr size_t SLOT_OFF = HD_OFF + HD_BYTES;
static constexpr size_t SLOT_BYTES = 64ull * 64 * 4;
static constexpr size_t FLG_OFF = SLOT_OFF + SLOT_BYTES;
static constexpr size_t FLG_BYTES = 256;
static constexpr size_t WL_OFF = FLG_OFF + FLG_BYTES;             // hdr int[8], u16 ent[8][512] @ +64
static constexpr size_t WL_BYTES = 8448;
static constexpr size_t CW_OFF = WL_OFF + WL_BYTES;
static constexpr size_t CW_BYTES = (size_t)CW_TOTAL * 2;
static constexpr size_t WH8_OFF = ((CW_OFF + CW_BYTES + 255) / 256) * 256;

struct PrepArgs {
  const void* src[26];
  int off[26];
  int cnt[26];
};

// =====================================================================
// P: prep — dtype detect, repack cw + wh8; last WG: slot_map + worklist
// (8-entry chunks, padded to multiple of 8).
// =====================================================================
__global__ __launch_bounds__(256)
void k_prep(PrepArgs pa, const uint32_t* __restrict__ cond, const uint32_t* __restrict__ emb,
            const void* __restrict__ whf_src, const void* __restrict__ whb_src,
            const int* __restrict__ p_idx, int* __restrict__ flags,
            bf16* __restrict__ cw, unsigned char* __restrict__ wh8,
            int* __restrict__ slot_map, int* __restrict__ wl) {
  int bx = blockIdx.x;
  int tid = threadIdx.x;
  __shared__ int votes[256];

  int c1 = 0;
  {
    uint32_t w0 = emb[tid * 2], w1 = emb[tid * 2 + 1];
    int e0 = (int)((w0 >> 7) & 0xFF), e1 = (int)((w1 >> 7) & 0xFF);
    c1 += (e0 >= 96 && e0 <= 130) ? 1 : 0;
    c1 += (e1 >= 96 && e1 <= 130) ? 1 : 0;
  }
  votes[tid] = c1;
  __syncthreads();
  __shared__ int f32w_s;
  if (tid == 0) {
    int s = 0;
    for (int i = 0; i < 256; i++) s += votes[i];
    f32w_s = (s < 256) ? 1 : 0;
  }
  __syncthreads();
  bool f32w = f32w_s != 0;

  if (bx == 0) {
    __syncthreads();
    int c0 = 0;
    {
      uint32_t w0 = cond[tid * 2], w1 = cond[tid * 2 + 1];
      int e0 = (int)((w0 >> 7) & 0xFF), e1 = (int)((w1 >> 7) & 0xFF);
      c0 += (e0 >= 96 && e0 <= 130) ? 1 : 0;
      c0 += (e1 >= 96 && e1 <= 130) ? 1 : 0;
    }
    votes[tid] = c0;
    __syncthreads();
    if (tid == 0) {
      int s = 0;
      for (int i = 0; i < 256; i++) s += votes[i];
      flags[0] = (s < 256) ? 1 : 0;
      flags[1] = f32w ? 1 : 0;
    }
  }

  if (bx < PREP_WGS) {
    int gidx = bx * 2048 + tid;
    for (int e = 0; e < 8; e++, gidx += 256) {
      if (gidx >= PREP_TOTAL) break;
      if (gidx < CW_TOTAL) {
        int rem = gidx, s = 0;
        while (s < 26 && rem >= pa.cnt[s]) { rem -= pa.cnt[s]; s++; }
        if (s < 26) {
          float v = f32w ? ((const float*)pa.src[s])[rem]
                         : (float)((const bf16*)pa.src[s])[rem];
          cw[pa.off[s] + rem] = (bf16)v;
        }
      } else {
        int i = gidx - CW_TOTAL;
        const void* src = (i < 196608) ? whf_src : whb_src;
        int k = (i < 196608) ? i : i - 196608;
        float v = f32w ? ((const float*)src)[k] : (float)((const bf16*)src)[k];
        wh8[i] = fp8_of(v);
      }
    }
    return;
  }

  // ---- bx == PREP_WGS: slot_map + worklist (8-entry chunks) ----
  __shared__ int pbuf[2048];
  __shared__ signed char sm[4096];
  __shared__ unsigned short entL[8 * 512];
  __shared__ int cntL[8];
  for (int i = tid; i < 2048; i += 256) pbuf[i] = p_idx[i];
  for (int i = tid; i < 4096; i += 256) sm[i] = -1;
  __syncthreads();
  if (tid < 64) {
    int n = tid, cnt = 0;
    for (int t = 0; t < 32; t++) {
      int p = pbuf[t * 64 + n];
      if (sm[n * 64 + p] < 0) sm[n * 64 + p] = (signed char)(cnt++);
    }
  }
  __syncthreads();
  for (int i = tid; i < 4096; i += 256) slot_map[i] = (int)sm[i];
  if (tid < 8) {
    int xcd = tid, cnt = 0;
    for (int roll = xcd * 8; roll < xcd * 8 + 8; roll++)
      for (int n = 0; n < 64; n++)
        if (sm[n * 64 + roll] >= 0) entL[xcd * 512 + (cnt++)] = (unsigned short)(n | (roll << 8));
    unsigned short pad = (unsigned short)((xcd * 8) << 8);
    while (cnt & 7) entL[xcd * 512 + (cnt++)] = pad;  // pad to chunk of 8
    cntL[xcd] = cnt;
  }
  __syncthreads();
  if (tid < 8) wl[tid] = cntL[tid] >> 3;  // number of 8-chunks
  unsigned short* we = (unsigned short*)((char*)wl + 64);
  for (int i = tid; i < 8 * 512; i += 256) we[i] = entL[i];
}

// =====================================================================
// XG: fused xi GEMM (bx<256, 768-stride layout) + dec gi MLP (bx>=256).
// =====================================================================
__global__ __launch_bounds__(256)
void k_xi_gi(const int* __restrict__ lines, const bf16* __restrict__ cw,
             const void* __restrict__ cond_raw, const int* __restrict__ flags,
             const int* __restrict__ a_idx, bf16* __restrict__ xi,
             float* __restrict__ gi) {
  int bx = blockIdx.x;
  int tid = threadIdx.x;
  int w = tid >> 6, l = tid & 63, quad = l >> 4, l15 = l & 15;
  __shared__ __attribute__((aligned(16))) bf16 s_a[32 * 328];
  __shared__ __attribute__((aligned(16))) bf16 s_b[32 * 264];

  if (bx < 256) {  // ---- xi GEMM ----
    int dir = bx & 1, rb = bx >> 1;
    const bf16* embed = cw + o_embed;
    const bf16* wi = cw + (dir ? o_wi_b : o_wi_f);
    const bf16* bi = cw + (dir ? o_bi_b : o_bi_f);
    bf16* xs = s_a;
    {
      int row = tid >> 3, seg = tid & 7;
      int grow = rb * 32 + row;
      int u = grow >> 6, n = grow & 63;
      int line = lines[n * 64 + u];
      const bf16* src = embed + (size_t)line * H_ + seg * 32;
      bf16* dst = xs + row * 264 + seg * 32;
#pragma unroll
      for (int e = 0; e < 4; e++) *(bf16x8*)(dst + e * 8) = *(const bf16x8*)(src + e * 8);
    }
    __syncthreads();
    f32x4 acc[2][12];
#pragma unroll
    for (int mt = 0; mt < 2; mt++)
#pragma unroll
      for (int nt = 0; nt < 12; nt++) acc[mt][nt] = f32x4{0.f, 0.f, 0.f, 0.f};
#pragma unroll
    for (int ks = 0; ks < 8; ks++) {
      int koff = ks * 32 + quad * 8;
      bf16x8 a0 = *(const bf16x8*)(xs + l15 * 264 + koff);
      bf16x8 a1 = *(const bf16x8*)(xs + (l15 + 16) * 264 + koff);
#pragma unroll
      for (int nt = 0; nt < 12; nt++) {
        int g = (w * 12 + nt) * 16 + l15;
        bf16x8 b = *(const bf16x8*)(wi + (size_t)g * H_ + koff);
        acc[0][nt] = mfma_bf16(a0, b, acc[0][nt]);
        acc[1][nt] = mfma_bf16(a1, b, acc[1][nt]);
      }
    }
    size_t base = (size_t)dir * 4096 * 768;
#pragma unroll
    for (int nt = 0; nt < 12; nt++) {
      int g = (w * 12 + nt) * 16 + l15;
      float bias = (float)bi[g];
#pragma unroll
      for (int mt = 0; mt < 2; mt++)
#pragma unroll
        for (int r = 0; r < 4; r++) {
          int m = mt * 16 + quad * 4 + r;
          xi[base + (size_t)(rb * 32 + m) * 768 + g] = (bf16)(acc[mt][nt][r] + bias);
        }
    }
    return;
  }

  // ---- gi MLP chain ----
  int rb = bx - 256;
  const bf16* aemb = cw + o_aemb;
  const bf16* f_w1 = cw + o_f_w1;
  const bf16* f_b1 = cw + o_f_b1;
  const bf16* f_w2 = cw + o_f_w2;
  const bf16* f_b2 = cw + o_f_b2;
  const bf16* cell_wi = cw + o_cell_wi;
  const bf16* cell_bi = cw + o_cell_bi;
  bool cf32 = flags[0] != 0;
  bf16* obs = s_a;
  bf16* xf1 = s_b;

  for (int e = tid; e < 32 * 320; e += 256) {
    int row = e / 320, col = e - row * 320;
    int grow = rb * 32 + row;
    int t = grow >> 6, n = grow & 63;
    float v;
    if (col < 64) {
      v = cf32 ? ((const float*)cond_raw)[(size_t)grow * 64 + col]
               : (float)((const bf16*)cond_raw)[(size_t)grow * 64 + col];
    } else {
      int ap = (t == 0) ? 0 : a_idx[(t - 1) * 64 + n];
      v = (float)aemb[ap * 256 + (col - 64)];
    }
    obs[row * 328 + col] = (bf16)v;
  }
  __syncthreads();
  {
    f32x4 acc[2][4];
#pragma unroll
    for (int mt = 0; mt < 2; mt++)
#pragma unroll
      for (int nt = 0; nt < 4; nt++) acc[mt][nt] = f32x4{0.f, 0.f, 0.f, 0.f};
#pragma unroll
    for (int ks = 0; ks < 10; ks++) {
      int koff = ks * 32 + quad * 8;
      bf16x8 a0 = *(const bf16x8*)(obs + l15 * 328 + koff);
      bf16x8 a1 = *(const bf16x8*)(obs + (l15 + 16) * 328 + koff);
#pragma unroll
      for (int nt = 0; nt < 4; nt++) {
        int g = (w * 4 + nt) * 16 + l15;
        bf16x8 b = *(const bf16x8*)(f_w1 + (size_t)g * 320 + koff);
        acc[0][nt] = mfma_bf16(a0, b, acc[0][nt]);
        acc[1][nt] = mfma_bf16(a1, b, acc[1][nt]);
      }
    }
#pragma unroll
    for (int nt = 0; nt < 4; nt++) {
      int g = (w * 4 + nt) * 16 + l15;
      float bias = (float)f_b1[g];
#pragma unroll
      for (int mt = 0; mt < 2; mt++)
#pragma unroll
        for (int r = 0; r < 4; r++) {
          int m = mt * 16 + quad * 4 + r;
          xf1[m * 264 + g] = (bf16)fmaxf(acc[mt][nt][r] + bias, 0.f);
        }
    }
  }
  __syncthreads();
  bf16* xf2 = obs;
  {
    f32x4 acc[2][4];
#pragma unroll
    for (int mt = 0; mt < 2; mt++)
#pragma unroll
      for (int nt = 0; nt < 4; nt++) acc[mt][nt] = f32x4{0.f, 0.f, 0.f, 0.f};
#pragma unroll
    for (int ks = 0; ks < 8; ks++) {
      int koff = ks * 32 + quad * 8;
      bf16x8 a0 = *(const bf16x8*)(xf1 + l15 * 264 + koff);
      bf16x8 a1 = *(const bf16x8*)(xf1 + (l15 + 16) * 264 + koff);
#pragma unroll
      for (int nt = 0; nt < 4; nt++) {
        int g = (w * 4 + nt) * 16 + l15;
        bf16x8 b = *(const bf16x8*)(f_w2 + (size_t)g * 256 + koff);
        acc[0][nt] = mfma_bf16(a0, b, acc[0][nt]);
        acc[1][nt] = mfma_bf16(a1, b, acc[1][nt]);
      }
    }
#pragma unroll
    for (int nt = 0; nt < 4; nt++) {
      int g = (w * 4 + nt) * 16 + l15;
      float bias = (float)f_b2[g];
#pragma unroll
      for (int mt = 0; mt < 2; mt++)
#pragma unroll
        for (int r = 0; r < 4; r++) {
          int m = mt * 16 + quad * 4 + r;
          xf2[m * 264 + g] = (bf16)fmaxf(acc[mt][nt][r] + bias, 0.f);
        }
    }
  }
  __syncthreads();
  {
    f32x4 acc[2][12];
#pragma unroll
    for (int mt = 0; mt < 2; mt++)
#pragma unroll
      for (int nt = 0; nt < 12; nt++) acc[mt][nt] = f32x4{0.f, 0.f, 0.f, 0.f};
#pragma unroll
    for (int ks = 0; ks < 8; ks++) {
      int koff = ks * 32 + quad * 8;
      bf16x8 a0 = *(const bf16x8*)(xf2 + l15 * 264 + koff);
      bf16x8 a1 = *(const bf16x8*)(xf2 + (l15 + 16) * 264 + koff);
#pragma unroll
      for (int nt = 0; nt < 12; nt++) {
        int g = (w * 12 + nt) * 16 + l15;
        bf16x8 b = *(const bf16x8*)(cell_wi + (size_t)g * 256 + koff);
        acc[0][nt] = mfma_bf16(a0, b, acc[0][nt]);
        acc[1][nt] = mfma_bf16(a1, b, acc[1][nt]);
      }
    }
#pragma unroll
    for (int nt = 0; nt < 12; nt++) {
      int g = (w * 12 + nt) * 16 + l15;
      float bias = (float)cell_bi[g];
#pragma unroll
      for (int mt = 0; mt < 2; mt++)
#pragma unroll
        for (int r = 0; r < 4; r++) {
          int m = mt * 16 + quad * 4 + r;
          gi[(size_t)(rb * 32 + m) * 768 + g] = acc[mt][nt][r] + bias;
        }
    }
  }
}

// =====================================================================
// M: fused bigru (bx<1024, 8-entry chunks duplicated into 16-row m-tile
// -> ~416 working WGs, 2 co-resident WGs/CU) + decoder GRU (bx>=1024).
// r6-proven step body: L2 weight pointers, LDS->uint32 K1c copy.
// =====================================================================
__global__ __launch_bounds__(1024, 8)
void k_main(const bf16* __restrict__ cw, const unsigned char* __restrict__ wh8,
            const bf16* __restrict__ xi, const int* __restrict__ slot_map,
            const int* __restrict__ wl, const float* __restrict__ gi,
            unsigned char* __restrict__ K1c, float* __restrict__ hdec) {
  int bx = blockIdx.x;
  int tid = threadIdx.x;
  int w = tid >> 6, l = tid & 63, quad = l >> 4, l15 = l & 15;
  int c = w * 16 + l15;
  __shared__ __attribute__((aligned(16))) unsigned char smem[2][16 * 264 * 2];

  if (bx < 1024) {  // ---------------- bigru ----------------
    int xcd = bx & 7, dir = (bx >> 3) & 1, slot = bx >> 4;  // slot in [0,64)
    if (slot >= wl[xcd]) return;
    const unsigned short* we =
        (const unsigned short*)((const char*)wl + 64) + xcd * 512 + slot * 8;
    const unsigned char* whd = wh8 + (size_t)dir * 196608;
    const bf16* bh = cw + (dir ? o_bh_b : o_bh_f);

    unsigned char (*hb)[16 * 264 * 2] = smem;
    for (int idx = tid; idx < 16 * 264; idx += 1024) hb[0][idx] = 0;

    // rows: entry index (quad*4+r) & 7 — rows 8..15 duplicate 0..7
    int rollv[4], nbase[4];
#pragma unroll
    for (int r = 0; r < 4; r++) {
      int e = we[(quad * 4 + r) & 7];
      rollv[r] = e >> 8;
      nbase[r] = (e & 255) * 768;
    }
    // copy row (crow & 7 duplicates are idempotent stores)
    int crow = tid >> 6, cseg = tid & 63;
    int ec = we[crow & 7];
    int n_c = ec & 255, roll_c = ec >> 8;
    int kslot = slot_map[n_c * 64 + roll_c];
    unsigned char* dstb = K1c + ((size_t)n_c * 32 + (kslot < 0 ? 0 : kslot)) * 32768 + cseg * 4;

    float hreg[4] = {0.f, 0.f, 0.f, 0.f};
    float bhv[3];
    const unsigned char* bp[3];
#pragma unroll
    for (int g = 0; g < 3; g++) {
      int grow = g * 256 + c;
      bhv[g] = (float)bh[grow];
      bp[g] = whd + (size_t)grow * 256 + quad * 8;
    }
    const bf16* xid = xi + (size_t)dir * 4096 * 768;
    __syncthreads();

    int cur = 0;
    for (int t = 0; t < 64; t++) {
      int j = dir ? (63 - t) : t;
      float xiv[3][4];
#pragma unroll
      for (int r = 0; r < 4; r++) {
        int u = dir ? ((63 - t - rollv[r]) & 63) : ((t - rollv[r]) & 63);
        const bf16* xr = xid + u * 49152 + nbase[r] + c;
#pragma unroll
        for (int g = 0; g < 3; g++) xiv[g][r] = (float)xr[g * 256];
      }
      f32x4 acc[3];
#pragma unroll
      for (int g = 0; g < 3; g++) acc[g] = f32x4{0.f, 0.f, 0.f, 0.f};
#pragma unroll
      for (int ks = 0; ks < 8; ks++) {
        int ko = ks * 32 + quad * 8;
        long a0 = *(const long*)(hb[cur] + l15 * 264 + ko);
#pragma unroll
        for (int g = 0; g < 3; g++) {
          long b = *(const long*)(bp[g] + ks * 32);
          acc[g] = mfma_fp8(a0, b, acc[g]);
        }
      }
      int nxt = cur ^ 1;
#pragma unroll
      for (int r = 0; r < 4; r++) {
        float rg = sigmoid_f(xiv[0][r] + acc[0][r] + bhv[0]);
        float zg = sigmoid_f(xiv[1][r] + acc[1][r] + bhv[1]);
        float ng = tanh_f(xiv[2][r] + rg * (acc[2][r] + bhv[2]));
        hreg[r] = (1.f - zg) * ng + zg * hreg[r];
        hb[nxt][(quad * 4 + r) * 264 + c] = fp8_of(hreg[r]);
      }
      __syncthreads();
      if (kslot >= 0) {
        *(uint32_t*)(dstb + (size_t)(j * 2 + dir) * 256) =
            *(const uint32_t*)(hb[nxt] + crow * 264 + cseg * 4);
      }
      cur = nxt;
    }
    return;
  }

  // ---------------- decoder GRU cell (4 WGs, M=16 n-rows) ----------------
  int nq = bx - 1024;
  const bf16* wh = cw + o_cell_wh;
  const bf16* bh = cw + o_cell_bh;
  bf16 (*hb)[16 * 264] = (bf16(*)[16 * 264])smem;
  for (int idx = tid; idx < 16 * 264; idx += 1024) hb[0][idx] = (bf16)0.f;

  float hreg[4] = {0.f, 0.f, 0.f, 0.f};
  float bhv[3];
  const bf16* bp[3];
#pragma unroll
  for (int g = 0; g < 3; g++) {
    int grow = g * 256 + c;
    bhv[g] = (float)bh[grow];
    bp[g] = wh + (size_t)grow * 256 + quad * 8;
  }
  __syncthreads();

  int cur = 0;
  for (int t = 0; t < 32; t++) {
    const float* gr = gi + ((size_t)t * 64 + nq * 16) * 768;
    float giv[3][4];
#pragma unroll
    for (int r = 0; r < 4; r++)
#pragma unroll
      for (int g = 0; g < 3; g++)
        giv[g][r] = gr[(quad * 4 + r) * 768 + g * 256 + c];

    f32x4 acc[3];
#pragma unroll
    for (int g = 0; g < 3; g++) acc[g] = f32x4{0.f, 0.f, 0.f, 0.f};
#pragma unroll
    for (int ks = 0; ks < 8; ks++) {
      int ko = ks * 32 + quad * 8;
      bf16x8 a0 = *(const bf16x8*)(hb[cur] + l15 * 264 + ko);
#pragma unroll
      for (int g = 0; g < 3; g++) {
        bf16x8 b = *(const bf16x8*)(bp[g] + ks * 32);
        acc[g] = mfma_bf16(a0, b, acc[g]);
      }
    }
    int nxt = cur ^ 1;
#pragma unroll
    for (int r = 0; r < 4; r++) {
      float rg = sigmoid_f(giv[0][r] + acc[0][r] + bhv[0]);
      float zg = sigmoid_f(giv[1][r] + acc[1][r] + bhv[1]);
      float ng = tanh_f(giv[2][r] + rg * (acc[2][r] + bhv[2]));
      float hnew = (1.f - zg) * ng + zg * hreg[r];
      hreg[r] = hnew;
      hb[nxt][(quad * 4 + r) * 264 + c] = (bf16)hnew;
      hdec[((size_t)t * 64 + nq * 16 + quad * 4 + r) * 256 + c] = hnew;
    }
    __syncthreads();
    cur = nxt;
  }
}

// =====================================================================
// PO: merged heads (bx<64) + attention (bx>=64, q computed locally).
// 2112 WGs x 256 thr. LDS aliased (38 KB).
// =====================================================================
__global__ __launch_bounds__(256)
void k_post(const float* __restrict__ hdec, const unsigned char* __restrict__ K1c,
            const int* __restrict__ slot_map, const int* __restrict__ flags,
            const int* __restrict__ a_idx, const int* __restrict__ p_idx,
            const bf16* __restrict__ cw, void* __restrict__ out_raw) {
  int bx = blockIdx.x;
  int tid = threadIdx.x;
  int w = tid >> 6, l = tid & 63, quad = l >> 4, l15 = l & 15;
  __shared__ __attribute__((aligned(16))) unsigned char sraw[38032];
  bool f32o = flags[1] != 0;

  if (bx < 64) {  // ---------------- heads ----------------
    int rb = bx;
    const bf16* pointer_w = cw + o_pointer_w;
    const bf16* pointer_b = cw + o_pointer_b;
    const bf16* critic_w = cw + o_critic_w;
    const bf16* critic_b = cw + o_critic_b;
    bf16* hsb = (bf16*)sraw;
    float* pls = (float*)(sraw + 16896);
    float* vred = (float*)(sraw + 16896 + 8448);

    for (int idx = tid; idx < 32 * 256; idx += 256) {
      int row = idx >> 8, col = idx & 255;
      hsb[row * 264 + col] = (bf16)hdec[(size_t)(rb * 32 + row) * 256 + col];
    }
    __syncthreads();

    {
      f32x4 acc[2];
      acc[0] = f32x4{0.f, 0.f, 0.f, 0.f};
      acc[1] = f32x4{0.f, 0.f, 0.f, 0.f};
      int g = w * 16 + l15;
#pragma unroll
      for (int ks = 0; ks < 8; ks++) {
        int koff = ks * 32 + quad * 8;
        bf16x8 a0 = *(const bf16x8*)(hsb + l15 * 264 + koff);
        bf16x8 a1 = *(const bf16x8*)(hsb + (l15 + 16) * 264 + koff);
        bf16x8 b = *(const bf16x8*)(pointer_w + (size_t)g * 256 + koff);
        acc[0] = mfma_bf16(a0, b, acc[0]);
        acc[1] = mfma_bf16(a1, b, acc[1]);
      }
      float bias = (float)pointer_b[g];
#pragma unroll
      for (int mt = 0; mt < 2; mt++)
#pragma unroll
        for (int r = 0; r < 4; r++) {
          int m = mt * 16 + quad * 4 + r;
          pls[m * 66 + g] = acc[mt][r] + bias;
        }
    }
    {
      int row = tid >> 3, seg = tid & 7;
      float acc = 0.f;
#pragma unroll
      for (int k = 0; k < 32; k++)
        acc += (float)hsb[row * 264 + seg * 32 + k] * (float)critic_w[seg * 32 + k];
      vred[row * 8 + seg] = acc;
    }
    __syncthreads();

    if (tid < 32) {
      float mx = -1e30f;
      for (int k = 0; k < 64; k++) mx = fmaxf(mx, pls[tid * 66 + k]);
      float sm = 0.f;
      for (int k = 0; k < 64; k++) {
        float e = __expf(pls[tid * 66 + k] - mx);
        pls[tid * 66 + k] = e;
        sm += e;
      }
      float inv = 1.f / sm;
      for (int k = 0; k < 64; k++) pls[tid * 66 + k] *= inv;
      float v = (float)critic_b[0];
      for (int s = 0; s < 8; s++) v += vred[tid * 8 + s];
      vred[tid * 8] = v;
    }
    __syncthreads();

    if (f32o) {
      float* ob = (float*)out_raw;
      if (tid < 32) {
        int grow = rb * 32 + tid;
        ob[(size_t)grow * 339 + 0] = (float)a_idx[grow];
        ob[(size_t)grow * 339 + 1] = (float)p_idx[grow];
        ob[(size_t)grow * 339 + 2] = vred[tid * 8];
      }
      for (int idx = tid; idx < 32 * 256; idx += 256) {
        int row = idx >> 8, col = idx & 255;
        int grow = rb * 32 + row;
        ob[(size_t)grow * 339 + 3 + col] = hdec[(size_t)grow * 256 + col];
      }
      for (int idx = tid; idx < 32 * 64; idx += 256) {
        int row = idx >> 6, col = idx & 63;
        ob[(size_t)(rb * 32 + row) * 339 + 275 + col] = pls[row * 66 + col];
      }
    } else {
      bf16* ob = (bf16*)out_raw;
      if (tid < 32) {
        int grow = rb * 32 + tid;
        ob[(size_t)grow * 339 + 0] = (bf16)(float)a_idx[grow];
        ob[(size_t)grow * 339 + 1] = (bf16)(float)p_idx[grow];
        ob[(size_t)grow * 339 + 2] = (bf16)vred[tid * 8];
      }
      for (int idx = tid; idx < 32 * 256; idx += 256) {
        int row = idx >> 8, col = idx & 255;
        int grow = rb * 32 + row;
        ob[(size_t)grow * 339 + 3 + col] = (bf16)hdec[(size_t)grow * 256 + col];
      }
      for (int idx = tid; idx < 32 * 64; idx += 256) {
        int row = idx >> 6, col = idx & 63;
        ob[(size_t)(rb * 32 + row) * 339 + 275 + col] = (bf16)pls[row * 66 + col];
      }
    }
    return;
  }

  // ---------------- attention ----------------
  int tn = bx - 64;
  int t = tn >> 6, n = tn & 63;
  const bf16* actor_w = cw + o_actor_w;
  const bf16* actor_b = cw + o_actor_b;
  const bf16* query_w = cw + o_query_w;
  const bf16* query_b = cw + o_query_b;

  unsigned char* ksb = sraw;
  float* hs = (float*)(sraw + 33792);
  float* qs = (float*)(sraw + 33792 + 1024);
  float* ls = (float*)(sraw + 33792 + 2048);
  float* sA = (float*)(sraw + 33792 + 3072);
  float* al = (float*)(sraw + 33792 + 4096);

  hs[tid] = hdec[((size_t)t * 64 + n) * 256 + tid];
  int p = p_idx[t * 64 + n];
  int slot = slot_map[n * 64 + p];
  {
    const uint32_t* kg = (const uint32_t*)(K1c + ((size_t)n * 32 + slot) * 32768);
#pragma unroll
    for (int e = 0; e < 8; e++) {
      int flat = (e * 256 + tid) * 16;
      int kk = flat >> 8, col = flat & 255;
      uint32_t w0 = kg[(flat >> 2) + 0], w1 = kg[(flat >> 2) + 1];
      uint32_t w2 = kg[(flat >> 2) + 2], w3 = kg[(flat >> 2) + 3];
      uint32_t* d0 = (uint32_t*)(ksb + kk * 264 + col);
      d0[0] = w0; d0[1] = w1; d0[2] = w2; d0[3] = w3;
    }
  }
  __syncthreads();

  {
    float acc = (float)query_b[tid];
    const bf16* qw = query_w + (size_t)tid * 256;
#pragma unroll 4
    for (int k0 = 0; k0 < 256; k0 += 8) {
      bf16x8 wv = *(const bf16x8*)(qw + k0);
#pragma unroll
      for (int e = 0; e < 8; e++) acc += (float)wv[e] * hs[k0 + e];
    }
    qs[tid] = acc;
  }
  __syncthreads();

  {
    int kk = tid & 127, hc = tid >> 7;
    const uint32_t* kr = (const uint32_t*)(ksb + kk * 264 + hc * 128);
    const float* qr = qs + hc * 128;
    float acc = 0.f;
#pragma unroll 8
    for (int u = 0; u < 32; u++) {
      uint32_t b4 = kr[u];
      acc += __builtin_amdgcn_cvt_f32_fp8(b4, 0) * qr[u * 4 + 0];
      acc += __builtin_amdgcn_cvt_f32_fp8(b4, 1) * qr[u * 4 + 1];
      acc += __builtin_amdgcn_cvt_f32_fp8(b4, 2) * qr[u * 4 + 2];
      acc += __builtin_amdgcn_cvt_f32_fp8(b4, 3) * qr[u * 4 + 3];
    }
    ls[tid] = acc;
  }
  __syncthreads();
  if (tid < 128) ls[tid] += ls[tid + 128];
  __syncthreads();

  float zzv;
  {
    const unsigned char* kc = ksb + (tid & ~3);
    int sh = (tid & 3) * 8;
    float acc = 0.f;
#pragma unroll 8
    for (int kk = 0; kk < 128; kk++) {
      uint32_t d = *(const uint32_t*)(kc + kk * 264);
      acc += ls[kk] * __builtin_amdgcn_cvt_f32_fp8((int)(d >> sh), 0);
    }
    zzv = acc;
  }
  __syncthreads();
  qs[tid] = zzv;
  __syncthreads();

  {
    int a = tid >> 4, e = tid & 15;
    const bf16* aw = actor_w + (size_t)a * 256 + e * 16;
    const float* zr = qs + e * 16;
    float acc = 0.f;
#pragma unroll
    for (int hh = 0; hh < 16; hh++) acc += (float)aw[hh] * zr[hh];
    sA[tid] = acc;
  }
  __syncthreads();
  if (tid < 16) {
    float lg = (float)actor_b[tid];
#pragma unroll
    for (int e = 0; e < 16; e++) lg += sA[tid * 16 + e];
    float mx = lg;
#pragma unroll
    for (int m = 8; m > 0; m >>= 1) mx = fmaxf(mx, __shfl_xor(mx, m, 16));
    float ex = __expf(lg - mx);
    float sm = ex;
#pragma unroll
    for (int m = 8; m > 0; m >>= 1) sm += __shfl_xor(sm, m, 16);
    al[tid] = ex / sm;
  }
  __syncthreads();

  if (tid < 16) {
    size_t off = (size_t)(t * 64 + n) * 339 + 259 + tid;
    if (f32o) ((float*)out_raw)[off] = al[tid];
    else ((bf16*)out_raw)[off] = (bf16)al[tid];
  }
}

// =====================================================================
extern "C" void kernel_launch(void* const* d_in, const int* in_sizes, int n_in,
                              void* d_out, int out_size, void* d_ws, size_t ws_size,
                              hipStream_t stream) {
  (void)in_sizes; (void)n_in; (void)out_size; (void)ws_size;
  const void* condition = d_in[0];
  const int* lines      = (const int*)d_in[1];
  const int* a_idx      = (const int*)d_in[2];
  const int* p_idx      = (const int*)d_in[3];

  char* ws = (char*)d_ws;
  bf16* xi            = (bf16*)(ws + XI_OFF);
  unsigned char* K1c  = (unsigned char*)(ws + K1_OFF);
  float* gi           = (float*)(ws + GI_OFF);
  float* hdec         = (float*)(ws + HD_OFF);
  int* slot_map       = (int*)(ws + SLOT_OFF);
  int* flags          = (int*)(ws + FLG_OFF);
  int* wl             = (int*)(ws + WL_OFF);
  bf16* cw            = (bf16*)(ws + CW_OFF);
  unsigned char* wh8  = (unsigned char*)(ws + WH8_OFF);

  static const int src_idx[26] = {4, 5, 6, 7, 8, 9, 10, 11, 12, 13, 14, 15, 16,
                                  17, 18, 19, 20, 21, 22, 23, 24, 25, 26, 27, 28, 29};
  static const int offs[26] = {o_embed, o_aemb, o_wi_f, o_wh_f, o_bi_f, o_bh_f,
                               o_wi_b, o_wh_b, o_bi_b, o_bh_b, o_f_w1, o_f_b1,
                               o_f_w2, o_f_b2, o_cell_wi, o_cell_wh, o_cell_bi,
                               o_cell_bh, o_critic_w, o_critic_b, o_pointer_w,
                               o_pointer_b, o_actor_w, o_actor_b, o_query_w, o_query_b};
  static const int cnts[26] = {32768, 4096, 196608, 196608, 768, 768,
                               196608, 196608, 768, 768, 81920, 256,
                               65536, 256, 196608, 196608, 768,
                               768, 256, 1, 16384, 64, 4096, 16, 65536, 256};
  PrepArgs pa;
  for (int i = 0; i < 26; i++) {
    pa.src[i] = d_in[src_idx[i]];
    pa.off[i] = offs[i];
    pa.cnt[i] = cnts[i];
  }

  k_prep<<<PREP_WGS + 1, 256, 0, stream>>>(pa, (const uint32_t*)condition,
                                           (const uint32_t*)d_in[4], d_in[7], d_in[11],
                                           p_idx, flags, cw, wh8, slot_map, wl);
  k_xi_gi<<<320, 256, 0, stream>>>(lines, cw, condition, flags, a_idx, xi, gi);
  k_main<<<1028, 1024, 0, stream>>>(cw, wh8, xi, slot_map, wl, gi, K1c, hdec);
  k_post<<<2112, 256, 0, stream>>>(hdec, K1c, slot_map, flags, a_idx, p_idx, cw, d_out);
}

// Round 10
// 413.970 us; speedup vs baseline: 2.3116x; 2.3116x over previous
//
#include <hip/hip_runtime.h>
#include <hip/hip_bf16.h>
#include <cstddef>
#include <cstdint>

// ---------- types ----------
typedef __bf16 bf16;
typedef bf16 bf16x8 __attribute__((ext_vector_type(8)));
typedef float f32x4 __attribute__((ext_vector_type(4)));

#define DEV static __device__ __forceinline__

DEV f32x4 mfma_bf16(bf16x8 a, bf16x8 b, f32x4 c) {
  return __builtin_amdgcn_mfma_f32_16x16x32_bf16(a, b, c, 0, 0, 0);
}
DEV f32x4 mfma_fp8(long a, long b, f32x4 c) {
  return __builtin_amdgcn_mfma_f32_16x16x32_fp8_fp8(a, b, c, 0, 0, 0);
}

// fast nonlinearities: v_rcp_f32 instead of IEEE divide (error ~1ulp,
// far below fp8/bf16 quantization noise in this pipeline)
DEV float sigmoid_f(float x) {
  return __builtin_amdgcn_rcpf(1.0f + __expf(-x));
}
DEV float tanh_f(float x) {
  float ax = fabsf(x);
  float e = __expf(-2.0f * ax);
  float t = 1.0f - 2.0f * e * __builtin_amdgcn_rcpf(1.0f + e);
  return copysignf(t, x);
}
DEV unsigned char fp8_of(float x) {
  return (unsigned char)(__builtin_amdgcn_cvt_pk_fp8_f32(x, x, 0, false) & 0xFF);
}

// ---------- problem constants: T=32,N=64,C=64,L=64,H=256,NA=16,NL=128 ----------
static constexpr int H_ = 256;

// ---------- canonical bf16 weight region: element offsets ----------
static constexpr int o_embed = 0;
static constexpr int o_aemb = 32768;
static constexpr int o_wi_f = 36864;
static constexpr int o_wh_f = 233472;
static constexpr int o_bi_f = 430080;
static constexpr int o_bh_f = 430848;
static constexpr int o_wi_b = 431616;
static constexpr int o_wh_b = 628224;
static constexpr int o_bi_b = 824832;
static constexpr int o_bh_b = 825600;
static constexpr int o_f_w1 = 826368;
static constexpr int o_f_b1 = 908288;
static constexpr int o_f_w2 = 908544;
static constexpr int o_f_b2 = 974080;
static constexpr int o_cell_wi = 974336;
static constexpr int o_cell_wh = 1170944;
static constexpr int o_cell_bi = 1367552;
static constexpr int o_cell_bh = 1368320;
static constexpr int o_critic_w = 1369088;
static constexpr int o_critic_b = 1369344;
static constexpr int o_pointer_w = 1369360;
static constexpr int o_pointer_b = 1385744;
static constexpr int o_actor_w = 1385808;
static constexpr int o_actor_b = 1389904;
static constexpr int o_query_w = 1389920;
static constexpr int o_query_b = 1455456;
static constexpr int CW_TOTAL = 1455712;
static constexpr int WH8_TOTAL = 393216;  // fp8 [2][768][256]
static constexpr int PREP_TOTAL = CW_TOTAL + WH8_TOTAL;
static constexpr int PREP_WGS = (PREP_TOTAL + 2047) / 2048;  // 903

// ---------- workspace layout (bytes) ----------
static constexpr size_t XI_OFF = 0;                               // bf16 [2][4096 grow][768]
static constexpr size_t XI_BYTES = 2ull * 4096 * 768 * 2;         // 12.58 MB
static constexpr size_t K1_OFF = XI_OFF + XI_BYTES;
static constexpr size_t K1_BYTES = 64ull * 32 * 128 * 256;        // 67.1 MB
static constexpr size_t GI_OFF = K1_OFF + K1_BYTES;
static constexpr size_t GI_BYTES = 32ull * 64 * 768 * 4;
static constexpr size_t HD_OFF = GI_OFF + GI_BYTES;
static constexpr size_t HD_BYTES = 32ull * 64 * 256 * 4;
static constexpr size_t SLOT_OFF = HD_OFF + HD_BYTES;
static constexpr size_t SLOT_BYTES = 64ull * 64 * 4;
static constexpr size_t FLG_OFF = SLOT_OFF + SLOT_BYTES;
static constexpr size_t FLG_BYTES = 256;
static constexpr size_t WL_OFF = FLG_OFF + FLG_BYTES;             // hdr int[8], u16 ent[8][512] @ +64
static constexpr size_t WL_BYTES = 8448;
static constexpr size_t CW_OFF = WL_OFF + WL_BYTES;
static constexpr size_t CW_BYTES = (size_t)CW_TOTAL * 2;
static constexpr size_t WH8_OFF = ((CW_OFF + CW_BYTES + 255) / 256) * 256;

struct PrepArgs {
  const void* src[26];
  int off[26];
  int cnt[26];
};

// =====================================================================
// P: prep — dtype detect, repack cw + wh8; last WG: slot_map + worklist
// (16-entry chunks, padded).
// =====================================================================
__global__ __launch_bounds__(256)
void k_prep(PrepArgs pa, const uint32_t* __restrict__ cond, const uint32_t* __restrict__ emb,
            const void* __restrict__ whf_src, const void* __restrict__ whb_src,
            const int* __restrict__ p_idx, int* __restrict__ flags,
            bf16* __restrict__ cw, unsigned char* __restrict__ wh8,
            int* __restrict__ slot_map, int* __restrict__ wl) {
  int bx = blockIdx.x;
  int tid = threadIdx.x;
  __shared__ int votes[256];

  int c1 = 0;
  {
    uint32_t w0 = emb[tid * 2], w1 = emb[tid * 2 + 1];
    int e0 = (int)((w0 >> 7) & 0xFF), e1 = (int)((w1 >> 7) & 0xFF);
    c1 += (e0 >= 96 && e0 <= 130) ? 1 : 0;
    c1 += (e1 >= 96 && e1 <= 130) ? 1 : 0;
  }
  votes[tid] = c1;
  __syncthreads();
  __shared__ int f32w_s;
  if (tid == 0) {
    int s = 0;
    for (int i = 0; i < 256; i++) s += votes[i];
    f32w_s = (s < 256) ? 1 : 0;
  }
  __syncthreads();
  bool f32w = f32w_s != 0;

  if (bx == 0) {
    __syncthreads();
    int c0 = 0;
    {
      uint32_t w0 = cond[tid * 2], w1 = cond[tid * 2 + 1];
      int e0 = (int)((w0 >> 7) & 0xFF), e1 = (int)((w1 >> 7) & 0xFF);
      c0 += (e0 >= 96 && e0 <= 130) ? 1 : 0;
      c0 += (e1 >= 96 && e1 <= 130) ? 1 : 0;
    }
    votes[tid] = c0;
    __syncthreads();
    if (tid == 0) {
      int s = 0;
      for (int i = 0; i < 256; i++) s += votes[i];
      flags[0] = (s < 256) ? 1 : 0;
      flags[1] = f32w ? 1 : 0;
    }
  }

  if (bx < PREP_WGS) {
    int gidx = bx * 2048 + tid;
    for (int e = 0; e < 8; e++, gidx += 256) {
      if (gidx >= PREP_TOTAL) break;
      if (gidx < CW_TOTAL) {
        int rem = gidx, s = 0;
        while (s < 26 && rem >= pa.cnt[s]) { rem -= pa.cnt[s]; s++; }
        if (s < 26) {
          float v = f32w ? ((const float*)pa.src[s])[rem]
                         : (float)((const bf16*)pa.src[s])[rem];
          cw[pa.off[s] + rem] = (bf16)v;
        }
      } else {
        int i = gidx - CW_TOTAL;
        const void* src = (i < 196608) ? whf_src : whb_src;
        int k = (i < 196608) ? i : i - 196608;
        float v = f32w ? ((const float*)src)[k] : (float)((const bf16*)src)[k];
        wh8[i] = fp8_of(v);
      }
    }
    return;
  }

  // ---- bx == PREP_WGS: slot_map + worklist (16-entry chunks) ----
  __shared__ int pbuf[2048];
  __shared__ signed char sm[4096];
  __shared__ unsigned short entL[8 * 512];
  __shared__ int cntL[8];
  for (int i = tid; i < 2048; i += 256) pbuf[i] = p_idx[i];
  for (int i = tid; i < 4096; i += 256) sm[i] = -1;
  __syncthreads();
  if (tid < 64) {
    int n = tid, cnt = 0;
    for (int t = 0; t < 32; t++) {
      int p = pbuf[t * 64 + n];
      if (sm[n * 64 + p] < 0) sm[n * 64 + p] = (signed char)(cnt++);
    }
  }
  __syncthreads();
  for (int i = tid; i < 4096; i += 256) slot_map[i] = (int)sm[i];
  if (tid < 8) {
    int xcd = tid, cnt = 0;
    for (int roll = xcd * 8; roll < xcd * 8 + 8; roll++)
      for (int n = 0; n < 64; n++)
        if (sm[n * 64 + roll] >= 0) entL[xcd * 512 + (cnt++)] = (unsigned short)(n | (roll << 8));
    unsigned short pad = (unsigned short)((xcd * 8) << 8);
    while (cnt & 15) entL[xcd * 512 + (cnt++)] = pad;  // pad to chunk of 16
    cntL[xcd] = cnt;
  }
  __syncthreads();
  if (tid < 8) wl[tid] = cntL[tid] >> 4;  // number of 16-chunks
  unsigned short* we = (unsigned short*)((char*)wl + 64);
  for (int i = tid; i < 8 * 512; i += 256) we[i] = entL[i];
}

// =====================================================================
// XG: fused xi GEMM (bx<256, 768-stride layout) + dec gi MLP (bx>=256).
// =====================================================================
__global__ __launch_bounds__(256)
void k_xi_gi(const int* __restrict__ lines, const bf16* __restrict__ cw,
             const void* __restrict__ cond_raw, const int* __restrict__ flags,
             const int* __restrict__ a_idx, bf16* __restrict__ xi,
             float* __restrict__ gi) {
  int bx = blockIdx.x;
  int tid = threadIdx.x;
  int w = tid >> 6, l = tid & 63, quad = l >> 4, l15 = l & 15;
  __shared__ __attribute__((aligned(16))) bf16 s_a[32 * 328];
  __shared__ __attribute__((aligned(16))) bf16 s_b[32 * 264];

  if (bx < 256) {  // ---- xi GEMM ----
    int dir = bx & 1, rb = bx >> 1;
    const bf16* embed = cw + o_embed;
    const bf16* wi = cw + (dir ? o_wi_b : o_wi_f);
    const bf16* bi = cw + (dir ? o_bi_b : o_bi_f);
    bf16* xs = s_a;
    {
      int row = tid >> 3, seg = tid & 7;
      int grow = rb * 32 + row;
      int u = grow >> 6, n = grow & 63;
      int line = lines[n * 64 + u];
      const bf16* src = embed + (size_t)line * H_ + seg * 32;
      bf16* dst = xs + row * 264 + seg * 32;
#pragma unroll
      for (int e = 0; e < 4; e++) *(bf16x8*)(dst + e * 8) = *(const bf16x8*)(src + e * 8);
    }
    __syncthreads();
    f32x4 acc[2][12];
#pragma unroll
    for (int mt = 0; mt < 2; mt++)
#pragma unroll
      for (int nt = 0; nt < 12; nt++) acc[mt][nt] = f32x4{0.f, 0.f, 0.f, 0.f};
#pragma unroll
    for (int ks = 0; ks < 8; ks++) {
      int koff = ks * 32 + quad * 8;
      bf16x8 a0 = *(const bf16x8*)(xs + l15 * 264 + koff);
      bf16x8 a1 = *(const bf16x8*)(xs + (l15 + 16) * 264 + koff);
#pragma unroll
      for (int nt = 0; nt < 12; nt++) {
        int g = (w * 12 + nt) * 16 + l15;
        bf16x8 b = *(const bf16x8*)(wi + (size_t)g * H_ + koff);
        acc[0][nt] = mfma_bf16(a0, b, acc[0][nt]);
        acc[1][nt] = mfma_bf16(a1, b, acc[1][nt]);
      }
    }
    size_t base = (size_t)dir * 4096 * 768;
#pragma unroll
    for (int nt = 0; nt < 12; nt++) {
      int g = (w * 12 + nt) * 16 + l15;
      float bias = (float)bi[g];
#pragma unroll
      for (int mt = 0; mt < 2; mt++)
#pragma unroll
        for (int r = 0; r < 4; r++) {
          int m = mt * 16 + quad * 4 + r;
          xi[base + (size_t)(rb * 32 + m) * 768 + g] = (bf16)(acc[mt][nt][r] + bias);
        }
    }
    return;
  }

  // ---- gi MLP chain ----
  int rb = bx - 256;
  const bf16* aemb = cw + o_aemb;
  const bf16* f_w1 = cw + o_f_w1;
  const bf16* f_b1 = cw + o_f_b1;
  const bf16* f_w2 = cw + o_f_w2;
  const bf16* f_b2 = cw + o_f_b2;
  const bf16* cell_wi = cw + o_cell_wi;
  const bf16* cell_bi = cw + o_cell_bi;
  bool cf32 = flags[0] != 0;
  bf16* obs = s_a;
  bf16* xf1 = s_b;

  for (int e = tid; e < 32 * 320; e += 256) {
    int row = e / 320, col = e - row * 320;
    int grow = rb * 32 + row;
    int t = grow >> 6, n = grow & 63;
    float v;
    if (col < 64) {
      v = cf32 ? ((const float*)cond_raw)[(size_t)grow * 64 + col]
               : (float)((const bf16*)cond_raw)[(size_t)grow * 64 + col];
    } else {
      int ap = (t == 0) ? 0 : a_idx[(t - 1) * 64 + n];
      v = (float)aemb[ap * 256 + (col - 64)];
    }
    obs[row * 328 + col] = (bf16)v;
  }
  __syncthreads();
  {
    f32x4 acc[2][4];
#pragma unroll
    for (int mt = 0; mt < 2; mt++)
#pragma unroll
      for (int nt = 0; nt < 4; nt++) acc[mt][nt] = f32x4{0.f, 0.f, 0.f, 0.f};
#pragma unroll
    for (int ks = 0; ks < 10; ks++) {
      int koff = ks * 32 + quad * 8;
      bf16x8 a0 = *(const bf16x8*)(obs + l15 * 328 + koff);
      bf16x8 a1 = *(const bf16x8*)(obs + (l15 + 16) * 328 + koff);
#pragma unroll
      for (int nt = 0; nt < 4; nt++) {
        int g = (w * 4 + nt) * 16 + l15;
        bf16x8 b = *(const bf16x8*)(f_w1 + (size_t)g * 320 + koff);
        acc[0][nt] = mfma_bf16(a0, b, acc[0][nt]);
        acc[1][nt] = mfma_bf16(a1, b, acc[1][nt]);
      }
    }
#pragma unroll
    for (int nt = 0; nt < 4; nt++) {
      int g = (w * 4 + nt) * 16 + l15;
      float bias = (float)f_b1[g];
#pragma unroll
      for (int mt = 0; mt < 2; mt++)
#pragma unroll
        for (int r = 0; r < 4; r++) {
          int m = mt * 16 + quad * 4 + r;
          xf1[m * 264 + g] = (bf16)fmaxf(acc[mt][nt][r] + bias, 0.f);
        }
    }
  }
  __syncthreads();
  bf16* xf2 = obs;
  {
    f32x4 acc[2][4];
#pragma unroll
    for (int mt = 0; mt < 2; mt++)
#pragma unroll
      for (int nt = 0; nt < 4; nt++) acc[mt][nt] = f32x4{0.f, 0.f, 0.f, 0.f};
#pragma unroll
    for (int ks = 0; ks < 8; ks++) {
      int koff = ks * 32 + quad * 8;
      bf16x8 a0 = *(const bf16x8*)(xf1 + l15 * 264 + koff);
      bf16x8 a1 = *(const bf16x8*)(xf1 + (l15 + 16) * 264 + koff);
#pragma unroll
      for (int nt = 0; nt < 4; nt++) {
        int g = (w * 4 + nt) * 16 + l15;
        bf16x8 b = *(const bf16x8*)(f_w2 + (size_t)g * 256 + koff);
        acc[0][nt] = mfma_bf16(a0, b, acc[0][nt]);
        acc[1][nt] = mfma_bf16(a1, b, acc[1][nt]);
      }
    }
#pragma unroll
    for (int nt = 0; nt < 4; nt++) {
      int g = (w * 4 + nt) * 16 + l15;
      float bias = (float)f_b2[g];
#pragma unroll
      for (int mt = 0; mt < 2; mt++)
#pragma unroll
        for (int r = 0; r < 4; r++) {
          int m = mt * 16 + quad * 4 + r;
          xf2[m * 264 + g] = (bf16)fmaxf(acc[mt][nt][r] + bias, 0.f);
        }
    }
  }
  __syncthreads();
  {
    f32x4 acc[2][12];
#pragma unroll
    for (int mt = 0; mt < 2; mt++)
#pragma unroll
      for (int nt = 0; nt < 12; nt++) acc[mt][nt] = f32x4{0.f, 0.f, 0.f, 0.f};
#pragma unroll
    for (int ks = 0; ks < 8; ks++) {
      int koff = ks * 32 + quad * 8;
      bf16x8 a0 = *(const bf16x8*)(xf2 + l15 * 264 + koff);
      bf16x8 a1 = *(const bf16x8*)(xf2 + (l15 + 16) * 264 + koff);
#pragma unroll
      for (int nt = 0; nt < 12; nt++) {
        int g = (w * 12 + nt) * 16 + l15;
        bf16x8 b = *(const bf16x8*)(cell_wi + (size_t)g * 256 + koff);
        acc[0][nt] = mfma_bf16(a0, b, acc[0][nt]);
        acc[1][nt] = mfma_bf16(a1, b, acc[1][nt]);
      }
    }
#pragma unroll
    for (int nt = 0; nt < 12; nt++) {
      int g = (w * 12 + nt) * 16 + l15;
      float bias = (float)cell_bi[g];
#pragma unroll
      for (int mt = 0; mt < 2; mt++)
#pragma unroll
        for (int r = 0; r < 4; r++) {
          int m = mt * 16 + quad * 4 + r;
          gi[(size_t)(rb * 32 + m) * 768 + g] = acc[mt][nt][r] + bias;
        }
    }
  }
}

// =====================================================================
// M: fused bigru (bx<512) + decoder GRU (bx>=512). 1024 thr.
// Exact r6-proven structure (203 us): 16-entry chunks, L2 weight
// pointers, LDS->uint32 K1c copy. Only change: rcp-based gates.
// =====================================================================
__global__ __launch_bounds__(1024)
void k_main(const bf16* __restrict__ cw, const unsigned char* __restrict__ wh8,
            const bf16* __restrict__ xi, const int* __restrict__ slot_map,
            const int* __restrict__ wl, const float* __restrict__ gi,
            unsigned char* __restrict__ K1c, float* __restrict__ hdec) {
  int bx = blockIdx.x;
  int tid = threadIdx.x;
  int w = tid >> 6, l = tid & 63, quad = l >> 4, l15 = l & 15;
  int c = w * 16 + l15;
  __shared__ __attribute__((aligned(16))) unsigned char smem[2][16 * 264 * 2];

  if (bx < 512) {  // ---------------- bigru ----------------
    int xcd = bx & 7, dir = (bx >> 3) & 1, slot = bx >> 4;
    if (slot >= wl[xcd]) return;
    const unsigned short* we = (const unsigned short*)((const char*)wl + 64) + xcd * 512 + slot * 16;
    const unsigned char* whd = wh8 + (size_t)dir * 196608;
    const bf16* bh = cw + (dir ? o_bh_b : o_bh_f);

    unsigned char (*hb)[16 * 264 * 2] = smem;
    for (int idx = tid; idx < 16 * 264; idx += 1024) hb[0][idx] = 0;

    int rollv[4], nbase[4];
#pragma unroll
    for (int r = 0; r < 4; r++) {
      int e = we[quad * 4 + r];
      rollv[r] = e >> 8;
      nbase[r] = (e & 255) * 768;
    }
    int crow = tid >> 6, cseg = tid & 63;
    int ec = we[crow];
    int n_c = ec & 255, roll_c = ec >> 8;
    int kslot = slot_map[n_c * 64 + roll_c];
    unsigned char* dstb = K1c + ((size_t)n_c * 32 + (kslot < 0 ? 0 : kslot)) * 32768 + cseg * 4;

    float hreg[4] = {0.f, 0.f, 0.f, 0.f};
    float bhv[3];
    const unsigned char* bp[3];
#pragma unroll
    for (int g = 0; g < 3; g++) {
      int grow = g * 256 + c;
      bhv[g] = (float)bh[grow];
      bp[g] = whd + (size_t)grow * 256 + quad * 8;
    }
    const bf16* xid = xi + (size_t)dir * 4096 * 768;
    __syncthreads();

    int cur = 0;
    for (int t = 0; t < 64; t++) {
      int j = dir ? (63 - t) : t;
      float xiv[3][4];
#pragma unroll
      for (int r = 0; r < 4; r++) {
        int u = dir ? ((63 - t - rollv[r]) & 63) : ((t - rollv[r]) & 63);
        const bf16* xr = xid + u * 49152 + nbase[r] + c;
#pragma unroll
        for (int g = 0; g < 3; g++) xiv[g][r] = (float)xr[g * 256];
      }
      f32x4 acc[3];
#pragma unroll
      for (int g = 0; g < 3; g++) acc[g] = f32x4{0.f, 0.f, 0.f, 0.f};
#pragma unroll
      for (int ks = 0; ks < 8; ks++) {
        int ko = ks * 32 + quad * 8;
        long a0 = *(const long*)(hb[cur] + l15 * 264 + ko);
#pragma unroll
        for (int g = 0; g < 3; g++) {
          long b = *(const long*)(bp[g] + ks * 32);
          acc[g] = mfma_fp8(a0, b, acc[g]);
        }
      }
      int nxt = cur ^ 1;
#pragma unroll
      for (int r = 0; r < 4; r++) {
        float rg = sigmoid_f(xiv[0][r] + acc[0][r] + bhv[0]);
        float zg = sigmoid_f(xiv[1][r] + acc[1][r] + bhv[1]);
        float ng = tanh_f(xiv[2][r] + rg * (acc[2][r] + bhv[2]));
        hreg[r] = (1.f - zg) * ng + zg * hreg[r];
        hb[nxt][(quad * 4 + r) * 264 + c] = fp8_of(hreg[r]);
      }
      __syncthreads();
      if (kslot >= 0) {
        *(uint32_t*)(dstb + (size_t)(j * 2 + dir) * 256) =
            *(const uint32_t*)(hb[nxt] + crow * 264 + cseg * 4);
      }
      cur = nxt;
    }
    return;
  }

  // ---------------- decoder GRU cell (4 WGs, M=16 n-rows) ----------------
  int nq = bx - 512;
  const bf16* wh = cw + o_cell_wh;
  const bf16* bh = cw + o_cell_bh;
  bf16 (*hb)[16 * 264] = (bf16(*)[16 * 264])smem;
  for (int idx = tid; idx < 16 * 264; idx += 1024) hb[0][idx] = (bf16)0.f;

  float hreg[4] = {0.f, 0.f, 0.f, 0.f};
  float bhv[3];
  const bf16* bp[3];
#pragma unroll
  for (int g = 0; g < 3; g++) {
    int grow = g * 256 + c;
    bhv[g] = (float)bh[grow];
    bp[g] = wh + (size_t)grow * 256 + quad * 8;
  }
  __syncthreads();

  int cur = 0;
  for (int t = 0; t < 32; t++) {
    const float* gr = gi + ((size_t)t * 64 + nq * 16) * 768;
    float giv[3][4];
#pragma unroll
    for (int r = 0; r < 4; r++)
#pragma unroll
      for (int g = 0; g < 3; g++)
        giv[g][r] = gr[(quad * 4 + r) * 768 + g * 256 + c];

    f32x4 acc[3];
#pragma unroll
    for (int g = 0; g < 3; g++) acc[g] = f32x4{0.f, 0.f, 0.f, 0.f};
#pragma unroll
    for (int ks = 0; ks < 8; ks++) {
      int ko = ks * 32 + quad * 8;
      bf16x8 a0 = *(const bf16x8*)(hb[cur] + l15 * 264 + ko);
#pragma unroll
      for (int g = 0; g < 3; g++) {
        bf16x8 b = *(const bf16x8*)(bp[g] + ks * 32);
        acc[g] = mfma_bf16(a0, b, acc[g]);
      }
    }
    int nxt = cur ^ 1;
#pragma unroll
    for (int r = 0; r < 4; r++) {
      float rg = sigmoid_f(giv[0][r] + acc[0][r] + bhv[0]);
      float zg = sigmoid_f(giv[1][r] + acc[1][r] + bhv[1]);
      float ng = tanh_f(giv[2][r] + rg * (acc[2][r] + bhv[2]));
      float hnew = (1.f - zg) * ng + zg * hreg[r];
      hreg[r] = hnew;
      hb[nxt][(quad * 4 + r) * 264 + c] = (bf16)hnew;
      hdec[((size_t)t * 64 + nq * 16 + quad * 4 + r) * 256 + c] = hnew;
    }
    __syncthreads();
    cur = nxt;
  }
}

// =====================================================================
// PO: merged heads (bx<64) + attention (bx>=64, q computed locally).
// 2112 WGs x 256 thr. LDS aliased (38 KB).
// =====================================================================
__global__ __launch_bounds__(256)
void k_post(const float* __restrict__ hdec, const unsigned char* __restrict__ K1c,
            const int* __restrict__ slot_map, const int* __restrict__ flags,
            const int* __restrict__ a_idx, const int* __restrict__ p_idx,
            const bf16* __restrict__ cw, void* __restrict__ out_raw) {
  int bx = blockIdx.x;
  int tid = threadIdx.x;
  int w = tid >> 6, l = tid & 63, quad = l >> 4, l15 = l & 15;
  __shared__ __attribute__((aligned(16))) unsigned char sraw[38032];
  bool f32o = flags[1] != 0;

  if (bx < 64) {  // ---------------- heads ----------------
    int rb = bx;
    const bf16* pointer_w = cw + o_pointer_w;
    const bf16* pointer_b = cw + o_pointer_b;
    const bf16* critic_w = cw + o_critic_w;
    const bf16* critic_b = cw + o_critic_b;
    bf16* hsb = (bf16*)sraw;
    float* pls = (float*)(sraw + 16896);
    float* vred = (float*)(sraw + 16896 + 8448);

    for (int idx = tid; idx < 32 * 256; idx += 256) {
      int row = idx >> 8, col = idx & 255;
      hsb[row * 264 + col] = (bf16)hdec[(size_t)(rb * 32 + row) * 256 + col];
    }
    __syncthreads();

    {
      f32x4 acc[2];
      acc[0] = f32x4{0.f, 0.f, 0.f, 0.f};
      acc[1] = f32x4{0.f, 0.f, 0.f, 0.f};
      int g = w * 16 + l15;
#pragma unroll
      for (int ks = 0; ks < 8; ks++) {
        int koff = ks * 32 + quad * 8;
        bf16x8 a0 = *(const bf16x8*)(hsb + l15 * 264 + koff);
        bf16x8 a1 = *(const bf16x8*)(hsb + (l15 + 16) * 264 + koff);
        bf16x8 b = *(const bf16x8*)(pointer_w + (size_t)g * 256 + koff);
        acc[0] = mfma_bf16(a0, b, acc[0]);
        acc[1] = mfma_bf16(a1, b, acc[1]);
      }
      float bias = (float)pointer_b[g];
#pragma unroll
      for (int mt = 0; mt < 2; mt++)
#pragma unroll
        for (int r = 0; r < 4; r++) {
          int m = mt * 16 + quad * 4 + r;
          pls[m * 66 + g] = acc[mt][r] + bias;
        }
    }
    {
      int row = tid >> 3, seg = tid & 7;
      float acc = 0.f;
#pragma unroll
      for (int k = 0; k < 32; k++)
        acc += (float)hsb[row * 264 + seg * 32 + k] * (float)critic_w[seg * 32 + k];
      vred[row * 8 + seg] = acc;
    }
    __syncthreads();

    if (tid < 32) {
      float mx = -1e30f;
      for (int k = 0; k < 64; k++) mx = fmaxf(mx, pls[tid * 66 + k]);
      float sm = 0.f;
      for (int k = 0; k < 64; k++) {
        float e = __expf(pls[tid * 66 + k] - mx);
        pls[tid * 66 + k] = e;
        sm += e;
      }
      float inv = __builtin_amdgcn_rcpf(sm);
      for (int k = 0; k < 64; k++) pls[tid * 66 + k] *= inv;
      float v = (float)critic_b[0];
      for (int s = 0; s < 8; s++) v += vred[tid * 8 + s];
      vred[tid * 8] = v;
    }
    __syncthreads();

    if (f32o) {
      float* ob = (float*)out_raw;
      if (tid < 32) {
        int grow = rb * 32 + tid;
        ob[(size_t)grow * 339 + 0] = (float)a_idx[grow];
        ob[(size_t)grow * 339 + 1] = (float)p_idx[grow];
        ob[(size_t)grow * 339 + 2] = vred[tid * 8];
      }
      for (int idx = tid; idx < 32 * 256; idx += 256) {
        int row = idx >> 8, col = idx & 255;
        int grow = rb * 32 + row;
        ob[(size_t)grow * 339 + 3 + col] = hdec[(size_t)grow * 256 + col];
      }
      for (int idx = tid; idx < 32 * 64; idx += 256) {
        int row = idx >> 6, col = idx & 63;
        ob[(size_t)(rb * 32 + row) * 339 + 275 + col] = pls[row * 66 + col];
      }
    } else {
      bf16* ob = (bf16*)out_raw;
      if (tid < 32) {
        int grow = rb * 32 + tid;
        ob[(size_t)grow * 339 + 0] = (bf16)(float)a_idx[grow];
        ob[(size_t)grow * 339 + 1] = (bf16)(float)p_idx[grow];
        ob[(size_t)grow * 339 + 2] = (bf16)vred[tid * 8];
      }
      for (int idx = tid; idx < 32 * 256; idx += 256) {
        int row = idx >> 8, col = idx & 255;
        int grow = rb * 32 + row;
        ob[(size_t)grow * 339 + 3 + col] = (bf16)hdec[(size_t)grow * 256 + col];
      }
      for (int idx = tid; idx < 32 * 64; idx += 256) {
        int row = idx >> 6, col = idx & 63;
        ob[(size_t)(rb * 32 + row) * 339 + 275 + col] = (bf16)pls[row * 66 + col];
      }
    }
    return;
  }

  // ---------------- attention ----------------
  int tn = bx - 64;
  int t = tn >> 6, n = tn & 63;
  const bf16* actor_w = cw + o_actor_w;
  const bf16* actor_b = cw + o_actor_b;
  const bf16* query_w = cw + o_query_w;
  const bf16* query_b = cw + o_query_b;

  unsigned char* ksb = sraw;
  float* hs = (float*)(sraw + 33792);
  float* qs = (float*)(sraw + 33792 + 1024);
  float* ls = (float*)(sraw + 33792 + 2048);
  float* sA = (float*)(sraw + 33792 + 3072);
  float* al = (float*)(sraw + 33792 + 4096);

  hs[tid] = hdec[((size_t)t * 64 + n) * 256 + tid];
  int p = p_idx[t * 64 + n];
  int slot = slot_map[n * 64 + p];
  {
    const uint32_t* kg = (const uint32_t*)(K1c + ((size_t)n * 32 + slot) * 32768);
#pragma unroll
    for (int e = 0; e < 8; e++) {
      int flat = (e * 256 + tid) * 16;
      int kk = flat >> 8, col = flat & 255;
      uint32_t w0 = kg[(flat >> 2) + 0], w1 = kg[(flat >> 2) + 1];
      uint32_t w2 = kg[(flat >> 2) + 2], w3 = kg[(flat >> 2) + 3];
      uint32_t* d0 = (uint32_t*)(ksb + kk * 264 + col);
      d0[0] = w0; d0[1] = w1; d0[2] = w2; d0[3] = w3;
    }
  }
  __syncthreads();

  {
    float acc = (float)query_b[tid];
    const bf16* qw = query_w + (size_t)tid * 256;
#pragma unroll 4
    for (int k0 = 0; k0 < 256; k0 += 8) {
      bf16x8 wv = *(const bf16x8*)(qw + k0);
#pragma unroll
      for (int e = 0; e < 8; e++) acc += (float)wv[e] * hs[k0 + e];
    }
    qs[tid] = acc;
  }
  __syncthreads();

  {
    int kk = tid & 127, hc = tid >> 7;
    const uint32_t* kr = (const uint32_t*)(ksb + kk * 264 + hc * 128);
    const float* qr = qs + hc * 128;
    float acc = 0.f;
#pragma unroll 8
    for (int u = 0; u < 32; u++) {
      uint32_t b4 = kr[u];
      acc += __builtin_amdgcn_cvt_f32_fp8(b4, 0) * qr[u * 4 + 0];
      acc += __builtin_amdgcn_cvt_f32_fp8(b4, 1) * qr[u * 4 + 1];
      acc += __builtin_amdgcn_cvt_f32_fp8(b4, 2) * qr[u * 4 + 2];
      acc += __builtin_amdgcn_cvt_f32_fp8(b4, 3) * qr[u * 4 + 3];
    }
    ls[tid] = acc;
  }
  __syncthreads();
  if (tid < 128) ls[tid] += ls[tid + 128];
  __syncthreads();

  float zzv;
  {
    const unsigned char* kc = ksb + (tid & ~3);
    int sh = (tid & 3) * 8;
    float acc = 0.f;
#pragma unroll 8
    for (int kk = 0; kk < 128; kk++) {
      uint32_t d = *(const uint32_t*)(kc + kk * 264);
      acc += ls[kk] * __builtin_amdgcn_cvt_f32_fp8((int)(d >> sh), 0);
    }
    zzv = acc;
  }
  __syncthreads();
  qs[tid] = zzv;
  __syncthreads();

  {
    int a = tid >> 4, e = tid & 15;
    const bf16* aw = actor_w + (size_t)a * 256 + e * 16;
    const float* zr = qs + e * 16;
    float acc = 0.f;
#pragma unroll
    for (int hh = 0; hh < 16; hh++) acc += (float)aw[hh] * zr[hh];
    sA[tid] = acc;
  }
  __syncthreads();
  if (tid < 16) {
    float lg = (float)actor_b[tid];
#pragma unroll
    for (int e = 0; e < 16; e++) lg += sA[tid * 16 + e];
    float mx = lg;
#pragma unroll
    for (int m = 8; m > 0; m >>= 1) mx = fmaxf(mx, __shfl_xor(mx, m, 16));
    float ex = __expf(lg - mx);
    float sm = ex;
#pragma unroll
    for (int m = 8; m > 0; m >>= 1) sm += __shfl_xor(sm, m, 16);
    al[tid] = ex * __builtin_amdgcn_rcpf(sm);
  }
  __syncthreads();

  if (tid < 16) {
    size_t off = (size_t)(t * 64 + n) * 339 + 259 + tid;
    if (f32o) ((float*)out_raw)[off] = al[tid];
    else ((bf16*)out_raw)[off] = (bf16)al[tid];
  }
}

// =====================================================================
extern "C" void kernel_launch(void* const* d_in, const int* in_sizes, int n_in,
                              void* d_out, int out_size, void* d_ws, size_t ws_size,
                              hipStream_t stream) {
  (void)in_sizes; (void)n_in; (void)out_size; (void)ws_size;
  const void* condition = d_in[0];
  const int* lines      = (const int*)d_in[1];
  const int* a_idx      = (const int*)d_in[2];
  const int* p_idx      = (const int*)d_in[3];

  char* ws = (char*)d_ws;
  bf16* xi            = (bf16*)(ws + XI_OFF);
  unsigned char* K1c  = (unsigned char*)(ws + K1_OFF);
  float* gi           = (float*)(ws + GI_OFF);
  float* hdec         = (float*)(ws + HD_OFF);
  int* slot_map       = (int*)(ws + SLOT_OFF);
  int* flags          = (int*)(ws + FLG_OFF);
  int* wl             = (int*)(ws + WL_OFF);
  bf16* cw            = (bf16*)(ws + CW_OFF);
  unsigned char* wh8  = (unsigned char*)(ws + WH8_OFF);

  static const int src_idx[26] = {4, 5, 6, 7, 8, 9, 10, 11, 12, 13, 14, 15, 16,
                                  17, 18, 19, 20, 21, 22, 23, 24, 25, 26, 27, 28, 29};
  static const int offs[26] = {o_embed, o_aemb, o_wi_f, o_wh_f, o_bi_f, o_bh_f,
                               o_wi_b, o_wh_b, o_bi_b, o_bh_b, o_f_w1, o_f_b1,
                               o_f_w2, o_f_b2, o_cell_wi, o_cell_wh, o_cell_bi,
                               o_cell_bh, o_critic_w, o_critic_b, o_pointer_w,
                               o_pointer_b, o_actor_w, o_actor_b, o_query_w, o_query_b};
  static const int cnts[26] = {32768, 4096, 196608, 196608, 768, 768,
                               196608, 196608, 768, 768, 81920, 256,
                               65536, 256, 196608, 196608, 768,
                               768, 256, 1, 16384, 64, 4096, 16, 65536, 256};
  PrepArgs pa;
  for (int i = 0; i < 26; i++) {
    pa.src[i] = d_in[src_idx[i]];
    pa.off[i] = offs[i];
    pa.cnt[i] = cnts[i];
  }

  k_prep<<<PREP_WGS + 1, 256, 0, stream>>>(pa, (const uint32_t*)condition,
                                           (const uint32_t*)d_in[4], d_in[7], d_in[11],
                                           p_idx, flags, cw, wh8, slot_map, wl);
  k_xi_gi<<<320, 256, 0, stream>>>(lines, cw, condition, flags, a_idx, xi, gi);
  k_main<<<516, 1024, 0, stream>>>(cw, wh8, xi, slot_map, wl, gi, K1c, hdec);
  k_post<<<2112, 256, 0, stream>>>(hdec, K1c, slot_map, flags, a_idx, p_idx, cw, d_out);
}

// Round 11
// 393.613 us; speedup vs baseline: 2.4311x; 1.0517x over previous
//
#include <hip/hip_runtime.h>
#include <hip/hip_bf16.h>
#include <cstddef>
#include <cstdint>

// ---------- types ----------
typedef __bf16 bf16;
typedef bf16 bf16x8 __attribute__((ext_vector_type(8)));
typedef float f32x4 __attribute__((ext_vector_type(4)));

#define DEV static __device__ __forceinline__

DEV f32x4 mfma_bf16(bf16x8 a, bf16x8 b, f32x4 c) {
  return __builtin_amdgcn_mfma_f32_16x16x32_bf16(a, b, c, 0, 0, 0);
}
DEV f32x4 mfma_fp8(long a, long b, f32x4 c) {
  return __builtin_amdgcn_mfma_f32_16x16x32_fp8_fp8(a, b, c, 0, 0, 0);
}

// fast nonlinearities: v_rcp_f32 instead of IEEE divide (error ~1ulp,
// far below fp8/bf16 quantization noise in this pipeline)
DEV float sigmoid_f(float x) {
  return __builtin_amdgcn_rcpf(1.0f + __expf(-x));
}
DEV float tanh_f(float x) {
  float ax = fabsf(x);
  float e = __expf(-2.0f * ax);
  float t = 1.0f - 2.0f * e * __builtin_amdgcn_rcpf(1.0f + e);
  return copysignf(t, x);
}
DEV unsigned char fp8_of(float x) {
  return (unsigned char)(__builtin_amdgcn_cvt_pk_fp8_f32(x, x, 0, false) & 0xFF);
}

// ---------- problem constants: T=32,N=64,C=64,L=64,H=256,NA=16,NL=128 ----------
static constexpr int H_ = 256;

// ---------- canonical bf16 weight region: element offsets ----------
static constexpr int o_embed = 0;
static constexpr int o_aemb = 32768;
static constexpr int o_wi_f = 36864;
static constexpr int o_wh_f = 233472;
static constexpr int o_bi_f = 430080;
static constexpr int o_bh_f = 430848;
static constexpr int o_wi_b = 431616;
static constexpr int o_wh_b = 628224;
static constexpr int o_bi_b = 824832;
static constexpr int o_bh_b = 825600;
static constexpr int o_f_w1 = 826368;
static constexpr int o_f_b1 = 908288;
static constexpr int o_f_w2 = 908544;
static constexpr int o_f_b2 = 974080;
static constexpr int o_cell_wi = 974336;
static constexpr int o_cell_wh = 1170944;
static constexpr int o_cell_bi = 1367552;
static constexpr int o_cell_bh = 1368320;
static constexpr int o_critic_w = 1369088;
static constexpr int o_critic_b = 1369344;
static constexpr int o_pointer_w = 1369360;
static constexpr int o_pointer_b = 1385744;
static constexpr int o_actor_w = 1385808;
static constexpr int o_actor_b = 1389904;
static constexpr int o_query_w = 1389920;
static constexpr int o_query_b = 1455456;
static constexpr int CW_TOTAL = 1455712;
static constexpr int WH8_TOTAL = 393216;  // fp8 [2][768][256]
static constexpr int PREP_TOTAL = CW_TOTAL + WH8_TOTAL;
static constexpr int PREP_WGS = (PREP_TOTAL + 2047) / 2048;  // 903

// ---------- workspace layout (bytes) ----------
static constexpr size_t XI_OFF = 0;                               // bf16 [2][4096 grow][768]
static constexpr size_t XI_BYTES = 2ull * 4096 * 768 * 2;         // 12.58 MB
static constexpr size_t K1_OFF = XI_OFF + XI_BYTES;
static constexpr size_t K1_BYTES = 64ull * 32 * 128 * 256;        // 67.1 MB
static constexpr size_t GI_OFF = K1_OFF + K1_BYTES;
static constexpr size_t GI_BYTES = 32ull * 64 * 768 * 4;
static constexpr size_t HD_OFF = GI_OFF + GI_BYTES;
static constexpr size_t HD_BYTES = 32ull * 64 * 256 * 4;
static constexpr size_t SLOT_OFF = HD_OFF + HD_BYTES;
static constexpr size_t SLOT_BYTES = 64ull * 64 * 4;
static constexpr size_t FLG_OFF = SLOT_OFF + SLOT_BYTES;
static constexpr size_t FLG_BYTES = 256;
static constexpr size_t WL_OFF = FLG_OFF + FLG_BYTES;             // hdr int[8], u16 ent[8][512] @ +64
static constexpr size_t WL_BYTES = 8448;
static constexpr size_t CW_OFF = WL_OFF + WL_BYTES;
static constexpr size_t CW_BYTES = (size_t)CW_TOTAL * 2;
static constexpr size_t WH8_OFF = ((CW_OFF + CW_BYTES + 255) / 256) * 256;

struct PrepArgs {
  const void* src[26];
  int off[26];
  int cnt[26];
};

// =====================================================================
// P: prep — dtype detect, repack cw + wh8; last WG: slot_map + worklist
// (16-entry chunks, padded).
// =====================================================================
__global__ __launch_bounds__(256)
void k_prep(PrepArgs pa, const uint32_t* __restrict__ cond, const uint32_t* __restrict__ emb,
            const void* __restrict__ whf_src, const void* __restrict__ whb_src,
            const int* __restrict__ p_idx, int* __restrict__ flags,
            bf16* __restrict__ cw, unsigned char* __restrict__ wh8,
            int* __restrict__ slot_map, int* __restrict__ wl) {
  int bx = blockIdx.x;
  int tid = threadIdx.x;
  __shared__ int votes[256];

  int c1 = 0;
  {
    uint32_t w0 = emb[tid * 2], w1 = emb[tid * 2 + 1];
    int e0 = (int)((w0 >> 7) & 0xFF), e1 = (int)((w1 >> 7) & 0xFF);
    c1 += (e0 >= 96 && e0 <= 130) ? 1 : 0;
    c1 += (e1 >= 96 && e1 <= 130) ? 1 : 0;
  }
  votes[tid] = c1;
  __syncthreads();
  __shared__ int f32w_s;
  if (tid == 0) {
    int s = 0;
    for (int i = 0; i < 256; i++) s += votes[i];
    f32w_s = (s < 256) ? 1 : 0;
  }
  __syncthreads();
  bool f32w = f32w_s != 0;

  if (bx == 0) {
    __syncthreads();
    int c0 = 0;
    {
      uint32_t w0 = cond[tid * 2], w1 = cond[tid * 2 + 1];
      int e0 = (int)((w0 >> 7) & 0xFF), e1 = (int)((w1 >> 7) & 0xFF);
      c0 += (e0 >= 96 && e0 <= 130) ? 1 : 0;
      c0 += (e1 >= 96 && e1 <= 130) ? 1 : 0;
    }
    votes[tid] = c0;
    __syncthreads();
    if (tid == 0) {
      int s = 0;
      for (int i = 0; i < 256; i++) s += votes[i];
      flags[0] = (s < 256) ? 1 : 0;
      flags[1] = f32w ? 1 : 0;
    }
  }

  if (bx < PREP_WGS) {
    int gidx = bx * 2048 + tid;
    for (int e = 0; e < 8; e++, gidx += 256) {
      if (gidx >= PREP_TOTAL) break;
      if (gidx < CW_TOTAL) {
        int rem = gidx, s = 0;
        while (s < 26 && rem >= pa.cnt[s]) { rem -= pa.cnt[s]; s++; }
        if (s < 26) {
          float v = f32w ? ((const float*)pa.src[s])[rem]
                         : (float)((const bf16*)pa.src[s])[rem];
          cw[pa.off[s] + rem] = (bf16)v;
        }
      } else {
        int i = gidx - CW_TOTAL;
        const void* src = (i < 196608) ? whf_src : whb_src;
        int k = (i < 196608) ? i : i - 196608;
        float v = f32w ? ((const float*)src)[k] : (float)((const bf16*)src)[k];
        wh8[i] = fp8_of(v);
      }
    }
    return;
  }

  // ---- bx == PREP_WGS: slot_map + worklist (16-entry chunks) ----
  __shared__ int pbuf[2048];
  __shared__ signed char sm[4096];
  __shared__ unsigned short entL[8 * 512];
  __shared__ int cntL[8];
  for (int i = tid; i < 2048; i += 256) pbuf[i] = p_idx[i];
  for (int i = tid; i < 4096; i += 256) sm[i] = -1;
  __syncthreads();
  if (tid < 64) {
    int n = tid, cnt = 0;
    for (int t = 0; t < 32; t++) {
      int p = pbuf[t * 64 + n];
      if (sm[n * 64 + p] < 0) sm[n * 64 + p] = (signed char)(cnt++);
    }
  }
  __syncthreads();
  for (int i = tid; i < 4096; i += 256) slot_map[i] = (int)sm[i];
  if (tid < 8) {
    int xcd = tid, cnt = 0;
    for (int roll = xcd * 8; roll < xcd * 8 + 8; roll++)
      for (int n = 0; n < 64; n++)
        if (sm[n * 64 + roll] >= 0) entL[xcd * 512 + (cnt++)] = (unsigned short)(n | (roll << 8));
    unsigned short pad = (unsigned short)((xcd * 8) << 8);
    while (cnt & 15) entL[xcd * 512 + (cnt++)] = pad;  // pad to chunk of 16
    cntL[xcd] = cnt;
  }
  __syncthreads();
  if (tid < 8) wl[tid] = cntL[tid] >> 4;  // number of 16-chunks
  unsigned short* we = (unsigned short*)((char*)wl + 64);
  for (int i = tid; i < 8 * 512; i += 256) we[i] = entL[i];
}

// =====================================================================
// XG: fused xi GEMM (bx<256, 768-stride layout) + dec gi MLP (bx>=256).
// =====================================================================
__global__ __launch_bounds__(256)
void k_xi_gi(const int* __restrict__ lines, const bf16* __restrict__ cw,
             const void* __restrict__ cond_raw, const int* __restrict__ flags,
             const int* __restrict__ a_idx, bf16* __restrict__ xi,
             float* __restrict__ gi) {
  int bx = blockIdx.x;
  int tid = threadIdx.x;
  int w = tid >> 6, l = tid & 63, quad = l >> 4, l15 = l & 15;
  __shared__ __attribute__((aligned(16))) bf16 s_a[32 * 328];
  __shared__ __attribute__((aligned(16))) bf16 s_b[32 * 264];

  if (bx < 256) {  // ---- xi GEMM ----
    int dir = bx & 1, rb = bx >> 1;
    const bf16* embed = cw + o_embed;
    const bf16* wi = cw + (dir ? o_wi_b : o_wi_f);
    const bf16* bi = cw + (dir ? o_bi_b : o_bi_f);
    bf16* xs = s_a;
    {
      int row = tid >> 3, seg = tid & 7;
      int grow = rb * 32 + row;
      int u = grow >> 6, n = grow & 63;
      int line = lines[n * 64 + u];
      const bf16* src = embed + (size_t)line * H_ + seg * 32;
      bf16* dst = xs + row * 264 + seg * 32;
#pragma unroll
      for (int e = 0; e < 4; e++) *(bf16x8*)(dst + e * 8) = *(const bf16x8*)(src + e * 8);
    }
    __syncthreads();
    f32x4 acc[2][12];
#pragma unroll
    for (int mt = 0; mt < 2; mt++)
#pragma unroll
      for (int nt = 0; nt < 12; nt++) acc[mt][nt] = f32x4{0.f, 0.f, 0.f, 0.f};
#pragma unroll
    for (int ks = 0; ks < 8; ks++) {
      int koff = ks * 32 + quad * 8;
      bf16x8 a0 = *(const bf16x8*)(xs + l15 * 264 + koff);
      bf16x8 a1 = *(const bf16x8*)(xs + (l15 + 16) * 264 + koff);
#pragma unroll
      for (int nt = 0; nt < 12; nt++) {
        int g = (w * 12 + nt) * 16 + l15;
        bf16x8 b = *(const bf16x8*)(wi + (size_t)g * H_ + koff);
        acc[0][nt] = mfma_bf16(a0, b, acc[0][nt]);
        acc[1][nt] = mfma_bf16(a1, b, acc[1][nt]);
      }
    }
    size_t base = (size_t)dir * 4096 * 768;
#pragma unroll
    for (int nt = 0; nt < 12; nt++) {
      int g = (w * 12 + nt) * 16 + l15;
      float bias = (float)bi[g];
#pragma unroll
      for (int mt = 0; mt < 2; mt++)
#pragma unroll
        for (int r = 0; r < 4; r++) {
          int m = mt * 16 + quad * 4 + r;
          xi[base + (size_t)(rb * 32 + m) * 768 + g] = (bf16)(acc[mt][nt][r] + bias);
        }
    }
    return;
  }

  // ---- gi MLP chain ----
  int rb = bx - 256;
  const bf16* aemb = cw + o_aemb;
  const bf16* f_w1 = cw + o_f_w1;
  const bf16* f_b1 = cw + o_f_b1;
  const bf16* f_w2 = cw + o_f_w2;
  const bf16* f_b2 = cw + o_f_b2;
  const bf16* cell_wi = cw + o_cell_wi;
  const bf16* cell_bi = cw + o_cell_bi;
  bool cf32 = flags[0] != 0;
  bf16* obs = s_a;
  bf16* xf1 = s_b;

  for (int e = tid; e < 32 * 320; e += 256) {
    int row = e / 320, col = e - row * 320;
    int grow = rb * 32 + row;
    int t = grow >> 6, n = grow & 63;
    float v;
    if (col < 64) {
      v = cf32 ? ((const float*)cond_raw)[(size_t)grow * 64 + col]
               : (float)((const bf16*)cond_raw)[(size_t)grow * 64 + col];
    } else {
      int ap = (t == 0) ? 0 : a_idx[(t - 1) * 64 + n];
      v = (float)aemb[ap * 256 + (col - 64)];
    }
    obs[row * 328 + col] = (bf16)v;
  }
  __syncthreads();
  {
    f32x4 acc[2][4];
#pragma unroll
    for (int mt = 0; mt < 2; mt++)
#pragma unroll
      for (int nt = 0; nt < 4; nt++) acc[mt][nt] = f32x4{0.f, 0.f, 0.f, 0.f};
#pragma unroll
    for (int ks = 0; ks < 10; ks++) {
      int koff = ks * 32 + quad * 8;
      bf16x8 a0 = *(const bf16x8*)(obs + l15 * 328 + koff);
      bf16x8 a1 = *(const bf16x8*)(obs + (l15 + 16) * 328 + koff);
#pragma unroll
      for (int nt = 0; nt < 4; nt++) {
        int g = (w * 4 + nt) * 16 + l15;
        bf16x8 b = *(const bf16x8*)(f_w1 + (size_t)g * 320 + koff);
        acc[0][nt] = mfma_bf16(a0, b, acc[0][nt]);
        acc[1][nt] = mfma_bf16(a1, b, acc[1][nt]);
      }
    }
#pragma unroll
    for (int nt = 0; nt < 4; nt++) {
      int g = (w * 4 + nt) * 16 + l15;
      float bias = (float)f_b1[g];
#pragma unroll
      for (int mt = 0; mt < 2; mt++)
#pragma unroll
        for (int r = 0; r < 4; r++) {
          int m = mt * 16 + quad * 4 + r;
          xf1[m * 264 + g] = (bf16)fmaxf(acc[mt][nt][r] + bias, 0.f);
        }
    }
  }
  __syncthreads();
  bf16* xf2 = obs;
  {
    f32x4 acc[2][4];
#pragma unroll
    for (int mt = 0; mt < 2; mt++)
#pragma unroll
      for (int nt = 0; nt < 4; nt++) acc[mt][nt] = f32x4{0.f, 0.f, 0.f, 0.f};
#pragma unroll
    for (int ks = 0; ks < 8; ks++) {
      int koff = ks * 32 + quad * 8;
      bf16x8 a0 = *(const bf16x8*)(xf1 + l15 * 264 + koff);
      bf16x8 a1 = *(const bf16x8*)(xf1 + (l15 + 16) * 264 + koff);
#pragma unroll
      for (int nt = 0; nt < 4; nt++) {
        int g = (w * 4 + nt) * 16 + l15;
        bf16x8 b = *(const bf16x8*)(f_w2 + (size_t)g * 256 + koff);
        acc[0][nt] = mfma_bf16(a0, b, acc[0][nt]);
        acc[1][nt] = mfma_bf16(a1, b, acc[1][nt]);
      }
    }
#pragma unroll
    for (int nt = 0; nt < 4; nt++) {
      int g = (w * 4 + nt) * 16 + l15;
      float bias = (float)f_b2[g];
#pragma unroll
      for (int mt = 0; mt < 2; mt++)
#pragma unroll
        for (int r = 0; r < 4; r++) {
          int m = mt * 16 + quad * 4 + r;
          xf2[m * 264 + g] = (bf16)fmaxf(acc[mt][nt][r] + bias, 0.f);
        }
    }
  }
  __syncthreads();
  {
    f32x4 acc[2][12];
#pragma unroll
    for (int mt = 0; mt < 2; mt++)
#pragma unroll
      for (int nt = 0; nt < 12; nt++) acc[mt][nt] = f32x4{0.f, 0.f, 0.f, 0.f};
#pragma unroll
    for (int ks = 0; ks < 8; ks++) {
      int koff = ks * 32 + quad * 8;
      bf16x8 a0 = *(const bf16x8*)(xf2 + l15 * 264 + koff);
      bf16x8 a1 = *(const bf16x8*)(xf2 + (l15 + 16) * 264 + koff);
#pragma unroll
      for (int nt = 0; nt < 12; nt++) {
        int g = (w * 12 + nt) * 16 + l15;
        bf16x8 b = *(const bf16x8*)(cell_wi + (size_t)g * 256 + koff);
        acc[0][nt] = mfma_bf16(a0, b, acc[0][nt]);
        acc[1][nt] = mfma_bf16(a1, b, acc[1][nt]);
      }
    }
#pragma unroll
    for (int nt = 0; nt < 12; nt++) {
      int g = (w * 12 + nt) * 16 + l15;
      float bias = (float)cell_bi[g];
#pragma unroll
      for (int mt = 0; mt < 2; mt++)
#pragma unroll
        for (int r = 0; r < 4; r++) {
          int m = mt * 16 + quad * 4 + r;
          gi[(size_t)(rb * 32 + m) * 768 + g] = acc[mt][nt][r] + bias;
        }
    }
  }
}

// =====================================================================
// M: fused bigru (bx<512) + decoder GRU (bx>=512). 1024 thr.
// r10 structure + ONE-STEP SOFTWARE PREFETCH of the gate inputs:
// t+1's xi/gi loads issue before t's MFMA; consumed next iteration,
// giving them a full step (~thousands of cycles) to complete.
// =====================================================================
__global__ __launch_bounds__(1024)
void k_main(const bf16* __restrict__ cw, const unsigned char* __restrict__ wh8,
            const bf16* __restrict__ xi, const int* __restrict__ slot_map,
            const int* __restrict__ wl, const float* __restrict__ gi,
            unsigned char* __restrict__ K1c, float* __restrict__ hdec) {
  int bx = blockIdx.x;
  int tid = threadIdx.x;
  int w = tid >> 6, l = tid & 63, quad = l >> 4, l15 = l & 15;
  int c = w * 16 + l15;
  __shared__ __attribute__((aligned(16))) unsigned char smem[2][16 * 264 * 2];

  if (bx < 512) {  // ---------------- bigru ----------------
    int xcd = bx & 7, dir = (bx >> 3) & 1, slot = bx >> 4;
    if (slot >= wl[xcd]) return;
    const unsigned short* we = (const unsigned short*)((const char*)wl + 64) + xcd * 512 + slot * 16;
    const unsigned char* whd = wh8 + (size_t)dir * 196608;
    const bf16* bh = cw + (dir ? o_bh_b : o_bh_f);

    unsigned char (*hb)[16 * 264 * 2] = smem;
    for (int idx = tid; idx < 16 * 264; idx += 1024) hb[0][idx] = 0;

    int rollv[4], nbase[4];
#pragma unroll
    for (int r = 0; r < 4; r++) {
      int e = we[quad * 4 + r];
      rollv[r] = e >> 8;
      nbase[r] = (e & 255) * 768;
    }
    int crow = tid >> 6, cseg = tid & 63;
    int ec = we[crow];
    int n_c = ec & 255, roll_c = ec >> 8;
    int kslot = slot_map[n_c * 64 + roll_c];
    unsigned char* dstb = K1c + ((size_t)n_c * 32 + (kslot < 0 ? 0 : kslot)) * 32768 + cseg * 4;

    float hreg[4] = {0.f, 0.f, 0.f, 0.f};
    float bhv[3];
    const unsigned char* bp[3];
#pragma unroll
    for (int g = 0; g < 3; g++) {
      int grow = g * 256 + c;
      bhv[g] = (float)bh[grow];
      bp[g] = whd + (size_t)grow * 256 + quad * 8;
    }
    const bf16* xid = xi + (size_t)dir * 4096 * 768;
    __syncthreads();

    // prefetch gate inputs for t=0 (raw bf16, convert at use)
    bf16 xpre[3][4];
#pragma unroll
    for (int r = 0; r < 4; r++) {
      int u = dir ? ((63 - rollv[r]) & 63) : ((0 - rollv[r]) & 63);
      const bf16* xr = xid + u * 49152 + nbase[r] + c;
#pragma unroll
      for (int g = 0; g < 3; g++) xpre[g][r] = xr[g * 256];
    }

    int cur = 0;
    for (int t = 0; t < 64; t++) {
      int j = dir ? (63 - t) : t;
      // issue t+1's loads now (wraps at t=63 to valid memory; unused)
      bf16 xnx[3][4];
#pragma unroll
      for (int r = 0; r < 4; r++) {
        int u = dir ? ((62 - t - rollv[r]) & 63) : ((t + 1 - rollv[r]) & 63);
        const bf16* xr = xid + u * 49152 + nbase[r] + c;
#pragma unroll
        for (int g = 0; g < 3; g++) xnx[g][r] = xr[g * 256];
      }

      f32x4 acc[3];
#pragma unroll
      for (int g = 0; g < 3; g++) acc[g] = f32x4{0.f, 0.f, 0.f, 0.f};
#pragma unroll
      for (int ks = 0; ks < 8; ks++) {
        int ko = ks * 32 + quad * 8;
        long a0 = *(const long*)(hb[cur] + l15 * 264 + ko);
#pragma unroll
        for (int g = 0; g < 3; g++) {
          long b = *(const long*)(bp[g] + ks * 32);
          acc[g] = mfma_fp8(a0, b, acc[g]);
        }
      }
      int nxt = cur ^ 1;
#pragma unroll
      for (int r = 0; r < 4; r++) {
        float rg = sigmoid_f((float)xpre[0][r] + acc[0][r] + bhv[0]);
        float zg = sigmoid_f((float)xpre[1][r] + acc[1][r] + bhv[1]);
        float ng = tanh_f((float)xpre[2][r] + rg * (acc[2][r] + bhv[2]));
        hreg[r] = (1.f - zg) * ng + zg * hreg[r];
        hb[nxt][(quad * 4 + r) * 264 + c] = fp8_of(hreg[r]);
      }
      __syncthreads();
      if (kslot >= 0) {
        *(uint32_t*)(dstb + (size_t)(j * 2 + dir) * 256) =
            *(const uint32_t*)(hb[nxt] + crow * 264 + cseg * 4);
      }
      // rotate prefetch registers (waitcnt for xnx lands here, after
      // a full step of MFMA+gates)
#pragma unroll
      for (int g = 0; g < 3; g++)
#pragma unroll
        for (int r = 0; r < 4; r++) xpre[g][r] = xnx[g][r];
      cur = nxt;
    }
    return;
  }

  // ---------------- decoder GRU cell (4 WGs, M=16 n-rows) ----------------
  int nq = bx - 512;
  const bf16* wh = cw + o_cell_wh;
  const bf16* bh = cw + o_cell_bh;
  bf16 (*hb)[16 * 264] = (bf16(*)[16 * 264])smem;
  for (int idx = tid; idx < 16 * 264; idx += 1024) hb[0][idx] = (bf16)0.f;

  float hreg[4] = {0.f, 0.f, 0.f, 0.f};
  float bhv[3];
  const bf16* bp[3];
  int goff[3][4];
#pragma unroll
  for (int g = 0; g < 3; g++) {
    int grow = g * 256 + c;
    bhv[g] = (float)bh[grow];
    bp[g] = wh + (size_t)grow * 256 + quad * 8;
#pragma unroll
    for (int r = 0; r < 4; r++)
      goff[g][r] = (quad * 4 + r) * 768 + grow;
  }
  const float* gbase = gi + (size_t)nq * 16 * 768;
  __syncthreads();

  // prefetch gi for t=0
  float gpre[3][4];
#pragma unroll
  for (int r = 0; r < 4; r++)
#pragma unroll
    for (int g = 0; g < 3; g++) gpre[g][r] = gbase[goff[g][r]];

  int cur = 0;
  for (int t = 0; t < 32; t++) {
    int tp = (t + 1) & 31;  // wraps at end; unused
    const float* gr = gbase + (size_t)tp * 64 * 768;
    float gnx[3][4];
#pragma unroll
    for (int r = 0; r < 4; r++)
#pragma unroll
      for (int g = 0; g < 3; g++) gnx[g][r] = gr[goff[g][r]];

    f32x4 acc[3];
#pragma unroll
    for (int g = 0; g < 3; g++) acc[g] = f32x4{0.f, 0.f, 0.f, 0.f};
#pragma unroll
    for (int ks = 0; ks < 8; ks++) {
      int ko = ks * 32 + quad * 8;
      bf16x8 a0 = *(const bf16x8*)(hb[cur] + l15 * 264 + ko);
#pragma unroll
      for (int g = 0; g < 3; g++) {
        bf16x8 b = *(const bf16x8*)(bp[g] + ks * 32);
        acc[g] = mfma_bf16(a0, b, acc[g]);
      }
    }
    int nxt = cur ^ 1;
#pragma unroll
    for (int r = 0; r < 4; r++) {
      float rg = sigmoid_f(gpre[0][r] + acc[0][r] + bhv[0]);
      float zg = sigmoid_f(gpre[1][r] + acc[1][r] + bhv[1]);
      float ng = tanh_f(gpre[2][r] + rg * (acc[2][r] + bhv[2]));
      float hnew = (1.f - zg) * ng + zg * hreg[r];
      hreg[r] = hnew;
      hb[nxt][(quad * 4 + r) * 264 + c] = (bf16)hnew;
      hdec[((size_t)t * 64 + nq * 16 + quad * 4 + r) * 256 + c] = hnew;
    }
    __syncthreads();
#pragma unroll
    for (int g = 0; g < 3; g++)
#pragma unroll
      for (int r = 0; r < 4; r++) gpre[g][r] = gnx[g][r];
    cur = nxt;
  }
}

// =====================================================================
// PO: merged heads (bx<64) + attention (bx>=64, q computed locally).
// 2112 WGs x 256 thr. LDS aliased (38 KB).
// =====================================================================
__global__ __launch_bounds__(256)
void k_post(const float* __restrict__ hdec, const unsigned char* __restrict__ K1c,
            const int* __restrict__ slot_map, const int* __restrict__ flags,
            const int* __restrict__ a_idx, const int* __restrict__ p_idx,
            const bf16* __restrict__ cw, void* __restrict__ out_raw) {
  int bx = blockIdx.x;
  int tid = threadIdx.x;
  int w = tid >> 6, l = tid & 63, quad = l >> 4, l15 = l & 15;
  __shared__ __attribute__((aligned(16))) unsigned char sraw[38032];
  bool f32o = flags[1] != 0;

  if (bx < 64) {  // ---------------- heads ----------------
    int rb = bx;
    const bf16* pointer_w = cw + o_pointer_w;
    const bf16* pointer_b = cw + o_pointer_b;
    const bf16* critic_w = cw + o_critic_w;
    const bf16* critic_b = cw + o_critic_b;
    bf16* hsb = (bf16*)sraw;
    float* pls = (float*)(sraw + 16896);
    float* vred = (float*)(sraw + 16896 + 8448);

    for (int idx = tid; idx < 32 * 256; idx += 256) {
      int row = idx >> 8, col = idx & 255;
      hsb[row * 264 + col] = (bf16)hdec[(size_t)(rb * 32 + row) * 256 + col];
    }
    __syncthreads();

    {
      f32x4 acc[2];
      acc[0] = f32x4{0.f, 0.f, 0.f, 0.f};
      acc[1] = f32x4{0.f, 0.f, 0.f, 0.f};
      int g = w * 16 + l15;
#pragma unroll
      for (int ks = 0; ks < 8; ks++) {
        int koff = ks * 32 + quad * 8;
        bf16x8 a0 = *(const bf16x8*)(hsb + l15 * 264 + koff);
        bf16x8 a1 = *(const bf16x8*)(hsb + (l15 + 16) * 264 + koff);
        bf16x8 b = *(const bf16x8*)(pointer_w + (size_t)g * 256 + koff);
        acc[0] = mfma_bf16(a0, b, acc[0]);
        acc[1] = mfma_bf16(a1, b, acc[1]);
      }
      float bias = (float)pointer_b[g];
#pragma unroll
      for (int mt = 0; mt < 2; mt++)
#pragma unroll
        for (int r = 0; r < 4; r++) {
          int m = mt * 16 + quad * 4 + r;
          pls[m * 66 + g] = acc[mt][r] + bias;
        }
    }
    {
      int row = tid >> 3, seg = tid & 7;
      float acc = 0.f;
#pragma unroll
      for (int k = 0; k < 32; k++)
        acc += (float)hsb[row * 264 + seg * 32 + k] * (float)critic_w[seg * 32 + k];
      vred[row * 8 + seg] = acc;
    }
    __syncthreads();

    if (tid < 32) {
      float mx = -1e30f;
      for (int k = 0; k < 64; k++) mx = fmaxf(mx, pls[tid * 66 + k]);
      float sm = 0.f;
      for (int k = 0; k < 64; k++) {
        float e = __expf(pls[tid * 66 + k] - mx);
        pls[tid * 66 + k] = e;
        sm += e;
      }
      float inv = __builtin_amdgcn_rcpf(sm);
      for (int k = 0; k < 64; k++) pls[tid * 66 + k] *= inv;
      float v = (float)critic_b[0];
      for (int s = 0; s < 8; s++) v += vred[tid * 8 + s];
      vred[tid * 8] = v;
    }
    __syncthreads();

    if (f32o) {
      float* ob = (float*)out_raw;
      if (tid < 32) {
        int grow = rb * 32 + tid;
        ob[(size_t)grow * 339 + 0] = (float)a_idx[grow];
        ob[(size_t)grow * 339 + 1] = (float)p_idx[grow];
        ob[(size_t)grow * 339 + 2] = vred[tid * 8];
      }
      for (int idx = tid; idx < 32 * 256; idx += 256) {
        int row = idx >> 8, col = idx & 255;
        int grow = rb * 32 + row;
        ob[(size_t)grow * 339 + 3 + col] = hdec[(size_t)grow * 256 + col];
      }
      for (int idx = tid; idx < 32 * 64; idx += 256) {
        int row = idx >> 6, col = idx & 63;
        ob[(size_t)(rb * 32 + row) * 339 + 275 + col] = pls[row * 66 + col];
      }
    } else {
      bf16* ob = (bf16*)out_raw;
      if (tid < 32) {
        int grow = rb * 32 + tid;
        ob[(size_t)grow * 339 + 0] = (bf16)(float)a_idx[grow];
        ob[(size_t)grow * 339 + 1] = (bf16)(float)p_idx[grow];
        ob[(size_t)grow * 339 + 2] = (bf16)vred[tid * 8];
      }
      for (int idx = tid; idx < 32 * 256; idx += 256) {
        int row = idx >> 8, col = idx & 255;
        int grow = rb * 32 + row;
        ob[(size_t)grow * 339 + 3 + col] = (bf16)hdec[(size_t)grow * 256 + col];
      }
      for (int idx = tid; idx < 32 * 64; idx += 256) {
        int row = idx >> 6, col = idx & 63;
        ob[(size_t)(rb * 32 + row) * 339 + 275 + col] = (bf16)pls[row * 66 + col];
      }
    }
    return;
  }

  // ---------------- attention ----------------
  int tn = bx - 64;
  int t = tn >> 6, n = tn & 63;
  const bf16* actor_w = cw + o_actor_w;
  const bf16* actor_b = cw + o_actor_b;
  const bf16* query_w = cw + o_query_w;
  const bf16* query_b = cw + o_query_b;

  unsigned char* ksb = sraw;
  float* hs = (float*)(sraw + 33792);
  float* qs = (float*)(sraw + 33792 + 1024);
  float* ls = (float*)(sraw + 33792 + 2048);
  float* sA = (float*)(sraw + 33792 + 3072);
  float* al = (float*)(sraw + 33792 + 4096);

  hs[tid] = hdec[((size_t)t * 64 + n) * 256 + tid];
  int p = p_idx[t * 64 + n];
  int slot = slot_map[n * 64 + p];
  {
    const uint32_t* kg = (const uint32_t*)(K1c + ((size_t)n * 32 + slot) * 32768);
#pragma unroll
    for (int e = 0; e < 8; e++) {
      int flat = (e * 256 + tid) * 16;
      int kk = flat >> 8, col = flat & 255;
      uint32_t w0 = kg[(flat >> 2) + 0], w1 = kg[(flat >> 2) + 1];
      uint32_t w2 = kg[(flat >> 2) + 2], w3 = kg[(flat >> 2) + 3];
      uint32_t* d0 = (uint32_t*)(ksb + kk * 264 + col);
      d0[0] = w0; d0[1] = w1; d0[2] = w2; d0[3] = w3;
    }
  }
  __syncthreads();

  {
    float acc = (float)query_b[tid];
    const bf16* qw = query_w + (size_t)tid * 256;
#pragma unroll 4
    for (int k0 = 0; k0 < 256; k0 += 8) {
      bf16x8 wv = *(const bf16x8*)(qw + k0);
#pragma unroll
      for (int e = 0; e < 8; e++) acc += (float)wv[e] * hs[k0 + e];
    }
    qs[tid] = acc;
  }
  __syncthreads();

  {
    int kk = tid & 127, hc = tid >> 7;
    const uint32_t* kr = (const uint32_t*)(ksb + kk * 264 + hc * 128);
    const float* qr = qs + hc * 128;
    float acc = 0.f;
#pragma unroll 8
    for (int u = 0; u < 32; u++) {
      uint32_t b4 = kr[u];
      acc += __builtin_amdgcn_cvt_f32_fp8(b4, 0) * qr[u * 4 + 0];
      acc += __builtin_amdgcn_cvt_f32_fp8(b4, 1) * qr[u * 4 + 1];
      acc += __builtin_amdgcn_cvt_f32_fp8(b4, 2) * qr[u * 4 + 2];
      acc += __builtin_amdgcn_cvt_f32_fp8(b4, 3) * qr[u * 4 + 3];
    }
    ls[tid] = acc;
  }
  __syncthreads();
  if (tid < 128) ls[tid] += ls[tid + 128];
  __syncthreads();

  float zzv;
  {
    const unsigned char* kc = ksb + (tid & ~3);
    int sh = (tid & 3) * 8;
    float acc = 0.f;
#pragma unroll 8
    for (int kk = 0; kk < 128; kk++) {
      uint32_t d = *(const uint32_t*)(kc + kk * 264);
      acc += ls[kk] * __builtin_amdgcn_cvt_f32_fp8((int)(d >> sh), 0);
    }
    zzv = acc;
  }
  __syncthreads();
  qs[tid] = zzv;
  __syncthreads();

  {
    int a = tid >> 4, e = tid & 15;
    const bf16* aw = actor_w + (size_t)a * 256 + e * 16;
    const float* zr = qs + e * 16;
    float acc = 0.f;
#pragma unroll
    for (int hh = 0; hh < 16; hh++) acc += (float)aw[hh] * zr[hh];
    sA[tid] = acc;
  }
  __syncthreads();
  if (tid < 16) {
    float lg = (float)actor_b[tid];
#pragma unroll
    for (int e = 0; e < 16; e++) lg += sA[tid * 16 + e];
    float mx = lg;
#pragma unroll
    for (int m = 8; m > 0; m >>= 1) mx = fmaxf(mx, __shfl_xor(mx, m, 16));
    float ex = __expf(lg - mx);
    float sm = ex;
#pragma unroll
    for (int m = 8; m > 0; m >>= 1) sm += __shfl_xor(sm, m, 16);
    al[tid] = ex * __builtin_amdgcn_rcpf(sm);
  }
  __syncthreads();

  if (tid < 16) {
    size_t off = (size_t)(t * 64 + n) * 339 + 259 + tid;
    if (f32o) ((float*)out_raw)[off] = al[tid];
    else ((bf16*)out_raw)[off] = (bf16)al[tid];
  }
}

// =====================================================================
extern "C" void kernel_launch(void* const* d_in, const int* in_sizes, int n_in,
                              void* d_out, int out_size, void* d_ws, size_t ws_size,
                              hipStream_t stream) {
  (void)in_sizes; (void)n_in; (void)out_size; (void)ws_size;
  const void* condition = d_in[0];
  const int* lines      = (const int*)d_in[1];
  const int* a_idx      = (const int*)d_in[2];
  const int* p_idx      = (const int*)d_in[3];

  char* ws = (char*)d_ws;
  bf16* xi            = (bf16*)(ws + XI_OFF);
  unsigned char* K1c  = (unsigned char*)(ws + K1_OFF);
  float* gi           = (float*)(ws + GI_OFF);
  float* hdec         = (float*)(ws + HD_OFF);
  int* slot_map       = (int*)(ws + SLOT_OFF);
  int* flags          = (int*)(ws + FLG_OFF);
  int* wl             = (int*)(ws + WL_OFF);
  bf16* cw            = (bf16*)(ws + CW_OFF);
  unsigned char* wh8  = (unsigned char*)(ws + WH8_OFF);

  static const int src_idx[26] = {4, 5, 6, 7, 8, 9, 10, 11, 12, 13, 14, 15, 16,
                                  17, 18, 19, 20, 21, 22, 23, 24, 25, 26, 27, 28, 29};
  static const int offs[26] = {o_embed, o_aemb, o_wi_f, o_wh_f, o_bi_f, o_bh_f,
                               o_wi_b, o_wh_b, o_bi_b, o_bh_b, o_f_w1, o_f_b1,
                               o_f_w2, o_f_b2, o_cell_wi, o_cell_wh, o_cell_bi,
                               o_cell_bh, o_critic_w, o_critic_b, o_pointer_w,
                               o_pointer_b, o_actor_w, o_actor_b, o_query_w, o_query_b};
  static const int cnts[26] = {32768, 4096, 196608, 196608, 768, 768,
                               196608, 196608, 768, 768, 81920, 256,
                               65536, 256, 196608, 196608, 768,
                               768, 256, 1, 16384, 64, 4096, 16, 65536, 256};
  PrepArgs pa;
  for (int i = 0; i < 26; i++) {
    pa.src[i] = d_in[src_idx[i]];
    pa.off[i] = offs[i];
    pa.cnt[i] = cnts[i];
  }

  k_prep<<<PREP_WGS + 1, 256, 0, stream>>>(pa, (const uint32_t*)condition,
                                           (const uint32_t*)d_in[4], d_in[7], d_in[11],
                                           p_idx, flags, cw, wh8, slot_map, wl);
  k_xi_gi<<<320, 256, 0, stream>>>(lines, cw, condition, flags, a_idx, xi, gi);
  k_main<<<516, 1024, 0, stream>>>(cw, wh8, xi, slot_map, wl, gi, K1c, hdec);
  k_post<<<2112, 256, 0, stream>>>(hdec, K1c, slot_map, flags, a_idx, p_idx, cw, d_out);
}